// Round 2
// baseline (211.297 us; speedup 1.0000x reference)
//
#include <hip/hip_runtime.h>
#include <math.h>

#define NB 4096
#define NA 8
#define BN (NB*NA)   // 32768

__device__ __forceinline__ float fast_tanh(float x){
    float e = __expf(2.0f*x);
    return 1.0f - 2.0f*__builtin_amdgcn_rcpf(e+1.0f);
}

#define FMA4(A, S, W) { (A).x += (S)*(W).x; (A).y += (S)*(W).y; (A).z += (S)*(W).z; (A).w += (S)*(W).w; }

// K0: M[e][f] = sum_d qw[e][d]*kw[f][d]; u[f] = sum_d qb[d]*kw[f][d]
__global__ __launch_bounds__(128) void k0_pre(const float* __restrict__ qw,
        const float* __restrict__ kw, const float* __restrict__ qb,
        float* __restrict__ M, float* __restrict__ u){
    int f = threadIdx.x;
    int e = blockIdx.x;
    if (e < 128){
        float acc = 0.f;
        for (int d=0; d<128; ++d) acc += qw[e*128+d]*kw[f*128+d];
        M[e*128+f] = acc;
    } else {
        float acc = 0.f;
        for (int d=0; d<128; ++d) acc += qb[d]*kw[f*128+d];
        u[f] = acc;
    }
}

// K1: conv encoder -> states[BN][48]  (cols: 0..31 conv2, 32..33 pos, 34..41 onehot, 42..47 zero)
__global__ __launch_bounds__(256) void k1_conv(const float* __restrict__ xin,
        const float* __restrict__ pos, const float* __restrict__ oneh,
        const float* __restrict__ w1, const float* __restrict__ b1,
        const float* __restrict__ w2, const float* __restrict__ b2,
        float* __restrict__ states){
    __shared__ float s_in[16*76];
    __shared__ float s_w1[432];
    __shared__ float s_b1[16];
    __shared__ float s_w2[4608];
    __shared__ float s_b2[32];
    __shared__ float s_h1[16*144];
    const int t = threadIdx.x;
    const int g0 = blockIdx.x*16;
    for (int u = t; u < 432; u += 256) s_w1[u] = w1[u];
    if (t < 16) s_b1[t] = b1[t];
    for (int u = t; u < 4608; u += 256) s_w2[u] = w2[u];
    if (t < 32) s_b2[t] = b2[t];
    for (int u = t; u < 1200; u += 256){
        int ag = u/75, r = u - ag*75;
        s_in[ag*76 + r] = xin[(size_t)g0*75 + u];
    }
    __syncthreads();
    for (int u = t; u < 2304; u += 256){
        int p9 = u % 9;
        int tmp = u / 9;
        int oc = tmp & 15;
        int ag = tmp >> 4;
        int y = p9 / 3, x = p9 - y*3;
        float acc = s_b1[oc];
        const float* wp = &s_w1[oc*27];
        const float* ip = &s_in[ag*76];
        #pragma unroll
        for (int ic=0; ic<3; ++ic)
          #pragma unroll
          for (int ky=0; ky<3; ++ky)
            #pragma unroll
            for (int kx=0; kx<3; ++kx)
                acc += ip[ic*25 + (y+ky)*5 + (x+kx)] * wp[ic*9 + ky*3 + kx];
        s_h1[ag*144 + oc*9 + p9] = (acc >= 0.f) ? acc : 0.01f*acc;
    }
    __syncthreads();
    for (int u = t; u < 512; u += 256){
        int oc = u & 31;
        int ag = u >> 5;
        float acc = s_b2[oc];
        const float* wp = &s_w2[oc*144];
        const float* hp = &s_h1[ag*144];
        #pragma unroll 16
        for (int k=0; k<144; ++k) acc += hp[k]*wp[k];
        acc = (acc >= 0.f) ? acc : 0.01f*acc;
        states[(size_t)(g0+ag)*48 + oc] = acc;
    }
    for (int u = t; u < 256; u += 256){
        int ag = u >> 4, k = u & 15;
        float v = 0.f;
        if (k < 2) v = pos[(size_t)(g0+ag)*2 + k];
        else if (k < 10) v = oneh[(size_t)(g0+ag)*8 + (k-2)];
        states[(size_t)(g0+ag)*48 + 32 + k] = v;
    }
}

// kA: fused E = tanh(states@se_w+se_b); T = E@M+u; weight = softmax(T·E^T / sqrt(128))
// 32 rows (= 4 full batches) per block. E, T never leave LDS.
__global__ __launch_bounds__(256) void kA(const float* __restrict__ states,
        const float* __restrict__ se_w, const float* __restrict__ se_b,
        const float* __restrict__ M, const float* __restrict__ u,
        float* __restrict__ wout){
    __shared__ float s_st[32*48];    // 6144 B
    __shared__ float s_E[32*132];    // 16896 B (pad to spread banks for attn)
    __shared__ float s_T[32*132];    // 16896 B
    const int t = threadIdx.x;
    const int r0 = blockIdx.x*32;
    for (int q=t; q<384; q+=256){
        int row = q/12, c = (q - row*12)*4;
        *(float4*)&s_st[row*48 + c] = *(const float4*)&states[(size_t)(r0+row)*48 + c];
    }
    __syncthreads();
    const int c4 = (t&31)*4;
    const int rb = t>>5;
    float4 acc[4];
    // GEMM1: E = tanh(states @ se_w + se_b), K=42
    #pragma unroll
    for (int i=0;i<4;++i) acc[i]=make_float4(0.f,0.f,0.f,0.f);
    for (int k4=0;k4<40;k4+=4){
        float4 w0=*(const float4*)&se_w[(k4+0)*128+c4];
        float4 w1=*(const float4*)&se_w[(k4+1)*128+c4];
        float4 w2=*(const float4*)&se_w[(k4+2)*128+c4];
        float4 w3=*(const float4*)&se_w[(k4+3)*128+c4];
        #pragma unroll
        for (int i=0;i<4;++i){
            float4 a=*(const float4*)&s_st[(rb+8*i)*48+k4];
            FMA4(acc[i],a.x,w0); FMA4(acc[i],a.y,w1);
            FMA4(acc[i],a.z,w2); FMA4(acc[i],a.w,w3);
        }
    }
    #pragma unroll
    for (int k=40;k<42;++k){
        float4 w=*(const float4*)&se_w[k*128+c4];
        #pragma unroll
        for (int i=0;i<4;++i){
            float s=s_st[(rb+8*i)*48+k];
            FMA4(acc[i],s,w);
        }
    }
    {
        float4 b=*(const float4*)&se_b[c4];
        #pragma unroll
        for (int i=0;i<4;++i){
            float4 o;
            o.x=fast_tanh(acc[i].x+b.x); o.y=fast_tanh(acc[i].y+b.y);
            o.z=fast_tanh(acc[i].z+b.z); o.w=fast_tanh(acc[i].w+b.w);
            *(float4*)&s_E[(rb+8*i)*132+c4]=o;
        }
    }
    __syncthreads();
    // GEMM2: T = E @ M + u, K=128
    #pragma unroll
    for (int i=0;i<4;++i) acc[i]=make_float4(0.f,0.f,0.f,0.f);
    for (int k4=0;k4<128;k4+=4){
        float4 w0=*(const float4*)&M[(k4+0)*128+c4];
        float4 w1=*(const float4*)&M[(k4+1)*128+c4];
        float4 w2=*(const float4*)&M[(k4+2)*128+c4];
        float4 w3=*(const float4*)&M[(k4+3)*128+c4];
        #pragma unroll
        for (int i=0;i<4;++i){
            float4 a=*(const float4*)&s_E[(rb+8*i)*132+k4];
            FMA4(acc[i],a.x,w0); FMA4(acc[i],a.y,w1);
            FMA4(acc[i],a.z,w2); FMA4(acc[i],a.w,w3);
        }
    }
    {
        float4 uu=*(const float4*)&u[c4];
        #pragma unroll
        for (int i=0;i<4;++i){
            float4 o;
            o.x=acc[i].x+uu.x; o.y=acc[i].y+uu.y;
            o.z=acc[i].z+uu.z; o.w=acc[i].w+uu.w;
            *(float4*)&s_T[(rb+8*i)*132+c4]=o;
        }
    }
    __syncthreads();
    // attention + softmax: one (batch, a, j) per thread
    {
        const int bq=t>>6, a=(t>>3)&7, j=t&7;
        const float* tp=&s_T[(bq*8+a)*132];
        const float* ep=&s_E[(bq*8+j)*132];
        float d=0.f;
        #pragma unroll 8
        for (int k=0;k<128;k+=4){
            float4 tv=*(const float4*)&tp[k];
            float4 ev=*(const float4*)&ep[k];
            d += tv.x*ev.x + tv.y*ev.y + tv.z*ev.z + tv.w*ev.w;
        }
        float s=d*0.08838834764831845f;
        float m=s;
        for (int off=1;off<8;off<<=1) m=fmaxf(m,__shfl_xor(m,off));
        float ex=__expf(s-m);
        float sum=ex;
        for (int off=1;off<8;off<<=1) sum+=__shfl_xor(sum,off);
        wout[(size_t)(blockIdx.x*4+bq)*64 + a*8 + j] = ex/sum;
    }
}

// kB: fused SAP(a/p) -> AV -> @f1_w -> (with weight) -> value. 32 rows = 4 batches per block.
// SAP/AV share one LDS buffer (in-place); A64/P64/b64 stay in LDS; writes only `value`.
__global__ __launch_bounds__(256) void kB(const float* __restrict__ states,
        const float* __restrict__ acts, const float* __restrict__ pols,
        const float* __restrict__ sap_w, const float* __restrict__ sap_b,
        const float* __restrict__ av_w, const float* __restrict__ av_b,
        const float* __restrict__ f1_w, const float* __restrict__ f1_b,
        const float* __restrict__ f2_w, const float* __restrict__ f2_b,
        const float* __restrict__ wgt, float* __restrict__ value){
    __shared__ float s_st[32*48];     // 6144 B
    __shared__ float s_ac[160], s_po[160];
    __shared__ float s_w[256];
    __shared__ float s_fc[128];       // f1_b | f2_w
    __shared__ float s_buf[32*128];   // 16384 B (SAP then AV, in place)
    __shared__ float s_A64[32*68];    // 8704 B (stride 68 spreads banks)
    __shared__ float s_P64[32*68];
    __shared__ float s_b64[32*68];
    const int t=threadIdx.x;
    const int r0=blockIdx.x*32;
    const int b0=blockIdx.x*4;
    for (int q=t;q<384;q+=256){
        int row=q/12, c=(q-row*12)*4;
        *(float4*)&s_st[row*48+c]=*(const float4*)&states[(size_t)(r0+row)*48+c];
    }
    if (t<160){ s_ac[t]=acts[(size_t)r0*5+t]; s_po[t]=pols[(size_t)r0*5+t]; }
    s_w[t]=wgt[(size_t)b0*64+t];
    if (t<64){ s_fc[t]=f1_b[t]; s_fc[64+t]=f2_w[t]; }
    __syncthreads();
    const int c4=(t&31)*4, rb=t>>5;
    const int c4f=(t&15)*4, rf=t>>4;
    for (int v=0;v<2;++v){
        const float* sx = v? s_po : s_ac;
        float* sd = v? s_P64 : s_A64;
        // GEMM1: SAP = tanh(states@sap_w[0:42] + x@sap_w[42:47] + sap_b), into s_buf
        float4 acc[4];
        #pragma unroll
        for (int i=0;i<4;++i) acc[i]=make_float4(0.f,0.f,0.f,0.f);
        for (int k4=0;k4<40;k4+=4){
            float4 w0=*(const float4*)&sap_w[(k4+0)*128+c4];
            float4 w1=*(const float4*)&sap_w[(k4+1)*128+c4];
            float4 w2=*(const float4*)&sap_w[(k4+2)*128+c4];
            float4 w3=*(const float4*)&sap_w[(k4+3)*128+c4];
            #pragma unroll
            for (int i=0;i<4;++i){
                float4 a=*(const float4*)&s_st[(rb+8*i)*48+k4];
                FMA4(acc[i],a.x,w0); FMA4(acc[i],a.y,w1);
                FMA4(acc[i],a.z,w2); FMA4(acc[i],a.w,w3);
            }
        }
        #pragma unroll
        for (int k=40;k<42;++k){
            float4 w=*(const float4*)&sap_w[k*128+c4];
            #pragma unroll
            for (int i=0;i<4;++i){
                float s=s_st[(rb+8*i)*48+k];
                FMA4(acc[i],s,w);
            }
        }
        #pragma unroll
        for (int k=0;k<5;++k){
            float4 w=*(const float4*)&sap_w[(42+k)*128+c4];
            #pragma unroll
            for (int i=0;i<4;++i){
                float s=sx[(rb+8*i)*5+k];
                FMA4(acc[i],s,w);
            }
        }
        {
            float4 b=*(const float4*)&sap_b[c4];
            #pragma unroll
            for (int i=0;i<4;++i){
                float4 o;
                o.x=fast_tanh(acc[i].x+b.x); o.y=fast_tanh(acc[i].y+b.y);
                o.z=fast_tanh(acc[i].z+b.z); o.w=fast_tanh(acc[i].w+b.w);
                *(float4*)&s_buf[(rb+8*i)*128+c4]=o;
            }
        }
        __syncthreads();
        // AV = tanh(SAP@av_w + av_b), K=128, keep in regs
        float4 acc2[4];
        #pragma unroll
        for (int i=0;i<4;++i) acc2[i]=make_float4(0.f,0.f,0.f,0.f);
        for (int k4=0;k4<128;k4+=4){
            float4 w0=*(const float4*)&av_w[(k4+0)*128+c4];
            float4 w1=*(const float4*)&av_w[(k4+1)*128+c4];
            float4 w2=*(const float4*)&av_w[(k4+2)*128+c4];
            float4 w3=*(const float4*)&av_w[(k4+3)*128+c4];
            #pragma unroll
            for (int i=0;i<4;++i){
                float4 a=*(const float4*)&s_buf[(rb+8*i)*128+k4];
                FMA4(acc2[i],a.x,w0); FMA4(acc2[i],a.y,w1);
                FMA4(acc2[i],a.z,w2); FMA4(acc2[i],a.w,w3);
            }
        }
        float4 o2[4];
        {
            float4 b=*(const float4*)&av_b[c4];
            #pragma unroll
            for (int i=0;i<4;++i){
                o2[i].x=fast_tanh(acc2[i].x+b.x); o2[i].y=fast_tanh(acc2[i].y+b.y);
                o2[i].z=fast_tanh(acc2[i].z+b.z); o2[i].w=fast_tanh(acc2[i].w+b.w);
            }
        }
        __syncthreads();   // all reads of SAP done -> reuse s_buf for AV
        #pragma unroll
        for (int i=0;i<4;++i) *(float4*)&s_buf[(rb+8*i)*128+c4]=o2[i];
        __syncthreads();
        // f1: dst = AV @ f1_w  (64 cols), K=128
        float4 acc3[2];
        #pragma unroll
        for (int i=0;i<2;++i) acc3[i]=make_float4(0.f,0.f,0.f,0.f);
        for (int k4=0;k4<128;k4+=4){
            float4 w0=*(const float4*)&f1_w[(k4+0)*64+c4f];
            float4 w1=*(const float4*)&f1_w[(k4+1)*64+c4f];
            float4 w2=*(const float4*)&f1_w[(k4+2)*64+c4f];
            float4 w3=*(const float4*)&f1_w[(k4+3)*64+c4f];
            #pragma unroll
            for (int i=0;i<2;++i){
                float4 a=*(const float4*)&s_buf[(rf+16*i)*128+k4];
                FMA4(acc3[i],a.x,w0); FMA4(acc3[i],a.y,w1);
                FMA4(acc3[i],a.z,w2); FMA4(acc3[i],a.w,w3);
            }
        }
        #pragma unroll
        for (int i=0;i<2;++i) *(float4*)&sd[(rf+16*i)*68+c4f]=acc3[i];
        __syncthreads();
    }
    // b64[bq][a][c] = sum_j w[bq,a,j]*A64[bq*8+j][c]
    for (int e=t;e<2048;e+=256){
        int bq=e>>9, rem=e&511, a=rem>>6, c=rem&63;
        float acc=0.f;
        #pragma unroll
        for (int j=0;j<8;++j) acc+=s_w[bq*64+a*8+j]*s_A64[(bq*8+j)*68+c];
        s_b64[(bq*8+a)*68+c]=acc;
    }
    __syncthreads();
    // value[bq][a][i] = f2_b + sum_c tanh(b64 + w_ai*(P-A) + f1_b)*f2_w
    {
        const int bq=t>>6, a=(t>>3)&7, i=t&7;
        float w_ai=s_w[bq*64+a*8+i];
        const float* pb=&s_b64[(bq*8+a)*68];
        const float* pA=&s_A64[(bq*8+i)*68];
        const float* pP=&s_P64[(bq*8+i)*68];
        float acc=0.f;
        #pragma unroll 8
        for (int c=0;c<64;++c){
            float d=pP[c]-pA[c];
            acc += fast_tanh(pb[c] + w_ai*d + s_fc[c]) * s_fc[64+c];
        }
        value[(size_t)b0*64 + t] = acc + f2_b[0];
    }
}

extern "C" void kernel_launch(void* const* d_in, const int* in_sizes, int n_in,
                              void* d_out, int out_size, void* d_ws, size_t ws_size,
                              hipStream_t stream){
    const float* agent_states = (const float*)d_in[0];
    const float* pos    = (const float*)d_in[1];
    const float* oneh   = (const float*)d_in[2];
    const float* pols   = (const float*)d_in[3];
    const float* acts   = (const float*)d_in[4];
    const float* w1     = (const float*)d_in[5];
    const float* b1     = (const float*)d_in[6];
    const float* w2     = (const float*)d_in[7];
    const float* b2     = (const float*)d_in[8];
    const float* se_w   = (const float*)d_in[9];
    const float* se_b   = (const float*)d_in[10];
    const float* key_w  = (const float*)d_in[11];
    const float* query_w= (const float*)d_in[13];
    const float* query_b= (const float*)d_in[14];
    const float* sap_w  = (const float*)d_in[15];
    const float* sap_b  = (const float*)d_in[16];
    const float* av_w   = (const float*)d_in[17];
    const float* av_b   = (const float*)d_in[18];
    const float* f1_w   = (const float*)d_in[19];
    const float* f1_b   = (const float*)d_in[20];
    const float* f2_w   = (const float*)d_in[21];
    const float* f2_b   = (const float*)d_in[22];

    float* ws = (float*)d_ws;
    float* M      = ws;                          // 16384
    float* u      = ws + 16384;                  // 128
    float* states = ws + 16512;                  // BN*48

    float* value = (float*)d_out;
    float* wout  = value + (size_t)NB*NA*NA;

    k0_pre <<<129, 128, 0, stream>>>(query_w, key_w, query_b, M, u);
    k1_conv<<<BN/16, 256, 0, stream>>>(agent_states, pos, oneh, w1, b1, w2, b2, states);
    kA     <<<BN/32, 256, 0, stream>>>(states, se_w, se_b, M, u, wout);
    kB     <<<BN/32, 256, 0, stream>>>(states, acts, pols, sap_w, sap_b, av_w, av_b,
                                       f1_w, f1_b, f2_w, f2_b, wout, value);
}

// Round 3
// 109.795 us; speedup vs baseline: 1.9245x; 1.9245x over previous
//
#include <hip/hip_runtime.h>
#include <math.h>

#define NB 4096
#define NA 8
#define BN (NB*NA)   // 32768

// ws layout (u32 words)
#define OFF_SE   0            // se pack:  8 tiles * 512
#define OFF_SAP  4096         // sap pack: 8 tiles * 512
#define OFF_AV   8192         // av pack:  8 tiles * 1024
#define OFF_F1   16384        // f1 pack:  4 tiles * 1024
#define OFF_M    20480        // M pack:   8 tiles * 1024
#define OFF_U    28672        // u: 128 floats
#define OFF_STA  28800        // statesA pack: 2048 tiles * 512
#define OFF_STP  (28800+1048576)

typedef short short8 __attribute__((ext_vector_type(8)));
typedef float f32x4 __attribute__((ext_vector_type(4)));

#define MFMA(a,b,c) __builtin_amdgcn_mfma_f32_16x16x32_bf16(a,b,c,0,0,0)

__device__ __forceinline__ float fast_tanh(float x){
    float e = __expf(2.0f*x);
    return 1.0f - 2.0f*__builtin_amdgcn_rcpf(e+1.0f);
}
__device__ __forceinline__ unsigned bfr(float x){
    unsigned u = __float_as_uint(x);
    return (u + 0x7fffu + ((u>>16)&1u)) >> 16;
}
__device__ __forceinline__ unsigned pk2(float lo, float hi){
    return bfr(lo) | (bfr(hi)<<16);
}
__device__ __forceinline__ float bf2f(unsigned short s){
    return __uint_as_float(((unsigned)s)<<16);
}
__device__ __forceinline__ short8 fragld(const unsigned* p){
    union { uint4 u; short8 s; } cv;
    cv.u = *(const uint4*)p;
    return cv.s;
}

// ---------------- kW: pack all weights as A-fragments (pack16 of W^T), compute M, u ----------
__global__ __launch_bounds__(256) void kW(const float* __restrict__ se_w,
        const float* __restrict__ sap_w, const float* __restrict__ av_w,
        const float* __restrict__ f1_w, const float* __restrict__ qw,
        const float* __restrict__ kw, const float* __restrict__ qb,
        unsigned* __restrict__ ws){
    int idx = blockIdx.x*256 + threadIdx.x;
    if (idx < 4096){                       // sePk (F=64 pad, rows f2=128)
        int w = idx, tile = w>>9, rem = w&511;
        int ft = rem>>6, r2 = (rem>>2)&15, wi = rem&3;
        int f2 = tile*16 + r2, f1 = ft*8 + wi*2;
        float lo = (f1   < 42)? se_w[f1*128+f2]     : 0.f;
        float hi = (f1+1 < 42)? se_w[(f1+1)*128+f2] : 0.f;
        ws[OFF_SE + w] = pk2(lo,hi);
    } else if (idx < 8192){                // sapPk (F=64 pad, limit 47)
        int w = idx-4096, tile = w>>9, rem = w&511;
        int ft = rem>>6, r2 = (rem>>2)&15, wi = rem&3;
        int f2 = tile*16 + r2, f1 = ft*8 + wi*2;
        float lo = (f1   < 47)? sap_w[f1*128+f2]     : 0.f;
        float hi = (f1+1 < 47)? sap_w[(f1+1)*128+f2] : 0.f;
        ws[OFF_SAP + w] = pk2(lo,hi);
    } else if (idx < 16384){               // avPk (F=128)
        int w = idx-8192, tile = w>>10, rem = w&1023;
        int ft = rem>>6, r2 = (rem>>2)&15, wi = rem&3;
        int f2 = tile*16 + r2, f1 = ft*8 + wi*2;
        ws[OFF_AV + w] = pk2(av_w[f1*128+f2], av_w[(f1+1)*128+f2]);
    } else if (idx < 20480){               // f1Pk (F=128, rows f2=64)
        int w = idx-16384, tile = w>>10, rem = w&1023;
        int ft = rem>>6, r2 = (rem>>2)&15, wi = rem&3;
        int f2 = tile*16 + r2, f1 = ft*8 + wi*2;
        ws[OFF_F1 + w] = pk2(f1_w[f1*64+f2], f1_w[(f1+1)*64+f2]);
    } else if (idx < 28672){               // MPk: M[e][f2] = qw[e]·kw[f2]
        int w = idx-20480, tile = w>>10, rem = w&1023;
        int ft = rem>>6, r2 = (rem>>2)&15, wi = rem&3;
        int f2 = tile*16 + r2, e0 = ft*8 + wi*2;
        float lo=0.f, hi=0.f;
        for (int d=0; d<128; ++d){
            float kv = kw[f2*128+d];
            lo += qw[e0*128+d]*kv;
            hi += qw[(e0+1)*128+d]*kv;
        }
        ws[OFF_M + w] = pk2(lo,hi);
    } else if (idx < 28800){               // u[f] = qb·kw[f]
        int f = idx-28672;
        float a = 0.f;
        for (int d=0; d<128; ++d) a += qb[d]*kw[f*128+d];
        ((float*)ws)[OFF_U + f] = a;
    }
}

// ---------------- k1: conv encoder -> statesA/statesP packs (16 rows = 1 tile per block) -----
__global__ __launch_bounds__(256) void k1_conv(const float* __restrict__ xin,
        const float* __restrict__ pos, const float* __restrict__ oneh,
        const float* __restrict__ acts, const float* __restrict__ pols,
        const float* __restrict__ w1, const float* __restrict__ b1,
        const float* __restrict__ w2, const float* __restrict__ b2,
        unsigned* __restrict__ stA, unsigned* __restrict__ stP){
    __shared__ float s_in[16*76];
    __shared__ float s_w1[432];
    __shared__ float s_b1[16];
    __shared__ float s_w2[4608];
    __shared__ float s_b2[32];
    __shared__ float s_h1[16*144];
    __shared__ float s_state[16*48];
    __shared__ float s_ap[160];
    const int t = threadIdx.x;
    const int g0 = blockIdx.x*16;
    for (int u = t; u < 432; u += 256) s_w1[u] = w1[u];
    if (t < 16) s_b1[t] = b1[t];
    for (int u = t; u < 4608; u += 256) s_w2[u] = w2[u];
    if (t < 32) s_b2[t] = b2[t];
    for (int u = t; u < 1200; u += 256){
        int ag = u/75, r = u - ag*75;
        s_in[ag*76 + r] = xin[(size_t)g0*75 + u];
    }
    for (int u = t; u < 160; u += 256){
        int ag = u/10, k = u - ag*10;
        s_ap[u] = (k<5)? acts[(size_t)(g0+ag)*5 + k] : pols[(size_t)(g0+ag)*5 + (k-5)];
    }
    __syncthreads();
    for (int u = t; u < 2304; u += 256){
        int p9 = u % 9;
        int tmp = u / 9;
        int oc = tmp & 15;
        int ag = tmp >> 4;
        int y = p9 / 3, x = p9 - y*3;
        float acc = s_b1[oc];
        const float* wp = &s_w1[oc*27];
        const float* ip = &s_in[ag*76];
        #pragma unroll
        for (int ic=0; ic<3; ++ic)
          #pragma unroll
          for (int ky=0; ky<3; ++ky)
            #pragma unroll
            for (int kx=0; kx<3; ++kx)
                acc += ip[ic*25 + (y+ky)*5 + (x+kx)] * wp[ic*9 + ky*3 + kx];
        s_h1[ag*144 + oc*9 + p9] = (acc >= 0.f) ? acc : 0.01f*acc;
    }
    __syncthreads();
    for (int u = t; u < 512; u += 256){
        int oc = u & 31;
        int ag = u >> 5;
        float acc = s_b2[oc];
        const float* wp = &s_w2[oc*144];
        const float* hp = &s_h1[ag*144];
        #pragma unroll 16
        for (int k=0; k<144; ++k) acc += hp[k]*wp[k];
        s_state[ag*48 + oc] = (acc >= 0.f) ? acc : 0.01f*acc;
    }
    {   // pose cols 32..47 (zeros at 42..47)
        int ag = t >> 4, k = t & 15;
        float v = 0.f;
        if (k < 2) v = pos[(size_t)(g0+ag)*2 + k];
        else if (k < 10) v = oneh[(size_t)(g0+ag)*8 + (k-2)];
        s_state[ag*48 + 32 + k] = v;
    }
    __syncthreads();
    // pack16: 512 words per tile, F=64 (f>=48 -> 0; f 42..46 -> act/pol)
    for (int q = t; q < 512; q += 256){
        int ft = q>>6, r = (q>>2)&15, wi = q&3;
        int f0 = ft*8 + wi*2;
        float v0 = (f0   < 48)? s_state[r*48 + f0]   : 0.f;
        float v1 = (f0+1 < 48)? s_state[r*48 + f0+1] : 0.f;
        float a0=v0, a1=v1, p0=v0, p1=v1;
        if (f0 >= 42 && f0 < 47){ a0 = s_ap[r*10 + (f0-42)]; p0 = s_ap[r*10 + 5 + (f0-42)]; }
        if (f0+1 >= 42 && f0+1 < 47){ a1 = s_ap[r*10 + (f0-41)]; p1 = s_ap[r*10 + 5 + (f0-41)]; }
        stA[(size_t)blockIdx.x*512 + q] = pk2(a0,a1);
        stP[(size_t)blockIdx.x*512 + q] = pk2(p0,p1);
    }
}

// ---------------- kA: E = tanh(states@se+b); T = E@M+u; weight = softmax(T·E^T/sqrt128) -----
// 64 rows/block, wave w owns rowtile w. No inter-wave deps after the staging barrier.
__global__ __launch_bounds__(256) void kA(const unsigned* __restrict__ ws,
        const float* __restrict__ se_b, float* __restrict__ wout){
    __shared__ unsigned sE[4096];   // 4 rowtiles * 1024 words
    __shared__ unsigned sT[4096];
    __shared__ float s_ub[256];     // u | se_b
    const int t = threadIdx.x;
    const int wv = t>>6, lane = t&63;
    const int g = lane>>4, c = lane&15;
    for (int q=t; q<256; q+=256) s_ub[q] = (q<128)? ((const float*)ws)[OFF_U+q] : se_b[q-128];
    __syncthreads();
    const int tile = blockIdx.x*4 + wv;
    const unsigned* stBase = ws + OFF_STA + (size_t)tile*512;
    // G1: E
    f32x4 acc[8];
    #pragma unroll
    for (int i=0;i<8;++i) acc[i] = (f32x4){0.f,0.f,0.f,0.f};
    #pragma unroll
    for (int kt=0; kt<2; ++kt){
        short8 bf = fragld(stBase + kt*256 + lane*4);
        #pragma unroll
        for (int ft=0; ft<8; ++ft){
            short8 af = fragld(ws + OFF_SE + ft*512 + kt*256 + lane*4);
            acc[ft] = MFMA(af, bf, acc[ft]);
        }
    }
    #pragma unroll
    for (int ft=0; ft<8; ++ft){
        const float* bp = &s_ub[128 + ft*16 + g*4];
        float d0 = fast_tanh(acc[ft][0]+bp[0]);
        float d1 = fast_tanh(acc[ft][1]+bp[1]);
        float d2 = fast_tanh(acc[ft][2]+bp[2]);
        float d3 = fast_tanh(acc[ft][3]+bp[3]);
        int word = wv*1024 + (2*ft + (g>>1))*64 + c*4 + (g&1)*2;
        *(uint2*)&sE[word] = make_uint2(pk2(d0,d1), pk2(d2,d3));
    }
    // G2: T = E@M + u
    f32x4 acc2[8];
    #pragma unroll
    for (int i=0;i<8;++i) acc2[i] = (f32x4){0.f,0.f,0.f,0.f};
    #pragma unroll
    for (int kt=0; kt<4; ++kt){
        short8 ef = fragld(&sE[wv*1024 + kt*256 + lane*4]);
        #pragma unroll
        for (int ft=0; ft<8; ++ft){
            short8 mf = fragld(ws + OFF_M + ft*1024 + kt*256 + lane*4);
            acc2[ft] = MFMA(mf, ef, acc2[ft]);
        }
    }
    #pragma unroll
    for (int ft=0; ft<8; ++ft){
        const float* up = &s_ub[ft*16 + g*4];
        int word = wv*1024 + (2*ft + (g>>1))*64 + c*4 + (g&1)*2;
        *(uint2*)&sT[word] = make_uint2(pk2(acc2[ft][0]+up[0], acc2[ft][1]+up[1]),
                                        pk2(acc2[ft][2]+up[2], acc2[ft][3]+up[3]));
    }
    // logits: L[a][j] = sum_d T[a][d] E[j][d]
    f32x4 L = (f32x4){0.f,0.f,0.f,0.f};
    #pragma unroll
    for (int kt=0; kt<4; ++kt){
        short8 tf = fragld(&sT[wv*1024 + kt*256 + lane*4]);
        short8 ef = fragld(&sE[wv*1024 + kt*256 + lane*4]);
        L = MFMA(tf, ef, L);
    }
    float sc[4];
    #pragma unroll
    for (int r=0;r<4;++r) sc[r] = L[r]*0.08838834764831845f;
    #pragma unroll
    for (int r=0;r<4;++r){
        float m = sc[r];
        m = fmaxf(m, __shfl_xor(m,1));
        m = fmaxf(m, __shfl_xor(m,2));
        m = fmaxf(m, __shfl_xor(m,4));
        float ex = __expf(sc[r]-m);
        float su = ex;
        su += __shfl_xor(su,1);
        su += __shfl_xor(su,2);
        su += __shfl_xor(su,4);
        sc[r] = ex/su;
    }
    if ((c>>3) == (g>>1)){
        int batch = tile*2 + (g>>1);
        int base = batch*64 + (c&7);
        #pragma unroll
        for (int r=0;r<4;++r)
            wout[base + ((g&1)*4 + r)*8] = sc[r];
    }
}

// ---------------- kB: SAP -> AV -> @f1 -> attention-mix -> value. 32 rows (4 batches)/block.
// waves: (variant v, rowtile rt). Barriers only at start and before final mix.
__global__ __launch_bounds__(256) void kB(const unsigned* __restrict__ ws,
        const float* __restrict__ sap_b, const float* __restrict__ av_b,
        const float* __restrict__ f1_b, const float* __restrict__ f2_w,
        const float* __restrict__ f2_b,
        const float* __restrict__ wout, float* __restrict__ value){
    __shared__ unsigned sSAP[4096];   // [v][rt][1024]
    __shared__ unsigned sAV[4096];
    __shared__ unsigned sA64[32*36];  // bf16 [row][72]
    __shared__ unsigned sP64[32*36];
    __shared__ float s_b64[32*68];
    __shared__ float s_w[256];
    __shared__ float s_bias[384];     // sap_b | av_b | f1_b | f2_w
    const int t = threadIdx.x;
    const int wv = t>>6, lane = t&63;
    const int g = lane>>4, c = lane&15;
    const int v = wv>>1, rt = wv&1;
    for (int q=t; q<384; q+=256)
        s_bias[q] = (q<128)? sap_b[q] : (q<256)? av_b[q-128] : (q<320)? f1_b[q-256] : f2_w[q-320];
    s_w[t] = wout[(size_t)blockIdx.x*256 + t];
    __syncthreads();
    const int tile = blockIdx.x*2 + rt;
    const unsigned* stBase = ws + (v? OFF_STP : OFF_STA) + (size_t)tile*512;
    unsigned* sapB = &sSAP[(v*2+rt)*1024];
    unsigned* avB  = &sAV[(v*2+rt)*1024];
    // G1: SAP = tanh(sap^T · x^T)
    f32x4 acc[8];
    #pragma unroll
    for (int i=0;i<8;++i) acc[i] = (f32x4){0.f,0.f,0.f,0.f};
    #pragma unroll
    for (int kt=0; kt<2; ++kt){
        short8 bf = fragld(stBase + kt*256 + lane*4);
        #pragma unroll
        for (int ft=0; ft<8; ++ft){
            short8 af = fragld(ws + OFF_SAP + ft*512 + kt*256 + lane*4);
            acc[ft] = MFMA(af, bf, acc[ft]);
        }
    }
    #pragma unroll
    for (int ft=0; ft<8; ++ft){
        const float* bp = &s_bias[ft*16 + g*4];
        float d0 = fast_tanh(acc[ft][0]+bp[0]);
        float d1 = fast_tanh(acc[ft][1]+bp[1]);
        float d2 = fast_tanh(acc[ft][2]+bp[2]);
        float d3 = fast_tanh(acc[ft][3]+bp[3]);
        int word = (2*ft + (g>>1))*64 + c*4 + (g&1)*2;
        *(uint2*)&sapB[word] = make_uint2(pk2(d0,d1), pk2(d2,d3));
    }
    // G2: AV = tanh(av^T · SAP^T)
    f32x4 acc2[8];
    #pragma unroll
    for (int i=0;i<8;++i) acc2[i] = (f32x4){0.f,0.f,0.f,0.f};
    #pragma unroll
    for (int kt=0; kt<4; ++kt){
        short8 bf = fragld(&sapB[kt*256 + lane*4]);
        #pragma unroll
        for (int ft=0; ft<8; ++ft){
            short8 af = fragld(ws + OFF_AV + ft*1024 + kt*256 + lane*4);
            acc2[ft] = MFMA(af, bf, acc2[ft]);
        }
    }
    #pragma unroll
    for (int ft=0; ft<8; ++ft){
        const float* bp = &s_bias[128 + ft*16 + g*4];
        float d0 = fast_tanh(acc2[ft][0]+bp[0]);
        float d1 = fast_tanh(acc2[ft][1]+bp[1]);
        float d2 = fast_tanh(acc2[ft][2]+bp[2]);
        float d3 = fast_tanh(acc2[ft][3]+bp[3]);
        int word = (2*ft + (g>>1))*64 + c*4 + (g&1)*2;
        *(uint2*)&avB[word] = make_uint2(pk2(d0,d1), pk2(d2,d3));
    }
    // G3: X64 = f1^T · AV^T  (64 cols)
    f32x4 acc3[4];
    #pragma unroll
    for (int i=0;i<4;++i) acc3[i] = (f32x4){0.f,0.f,0.f,0.f};
    #pragma unroll
    for (int kt=0; kt<4; ++kt){
        short8 bf = fragld(&avB[kt*256 + lane*4]);
        #pragma unroll
        for (int ft=0; ft<4; ++ft){
            short8 af = fragld(ws + OFF_F1 + ft*1024 + kt*256 + lane*4);
            acc3[ft] = MFMA(af, bf, acc3[ft]);
        }
    }
    {
        unsigned* dst = v? sP64 : sA64;
        int row = rt*16 + c;
        #pragma unroll
        for (int ft=0; ft<4; ++ft){
            int idx = row*36 + ft*8 + 2*g;
            *(uint2*)&dst[idx] = make_uint2(pk2(acc3[ft][0], acc3[ft][1]),
                                            pk2(acc3[ft][2], acc3[ft][3]));
        }
    }
    __syncthreads();
    // b64[bq][a][c] = sum_j w[bq,a,j] * A64[bq*8+j][c]
    const unsigned short* A16 = (const unsigned short*)sA64;
    const unsigned short* P16 = (const unsigned short*)sP64;
    #pragma unroll
    for (int k=0; k<8; ++k){
        int e = t + 256*k;
        int bq = e>>9, a = (e>>6)&7, cc = e&63;
        const float* wp = &s_w[bq*64 + a*8];
        float acc4 = 0.f;
        #pragma unroll
        for (int j=0;j<8;++j) acc4 += wp[j]*bf2f(A16[(bq*8+j)*72 + cc]);
        s_b64[(bq*8+a)*68 + cc] = acc4;
    }
    __syncthreads();
    {
        int bq = t>>6, a = (t>>3)&7, i = t&7;
        float w_ai = s_w[bq*64 + a*8 + i];
        const float* pb = &s_b64[(bq*8+a)*68];
        const unsigned short* pA = &A16[(bq*8+i)*72];
        const unsigned short* pP = &P16[(bq*8+i)*72];
        float acc5 = 0.f;
        #pragma unroll 8
        for (int cc=0; cc<64; ++cc){
            float dd = bf2f(pP[cc]) - bf2f(pA[cc]);
            acc5 += fast_tanh(pb[cc] + w_ai*dd + s_bias[256+cc]) * s_bias[320+cc];
        }
        value[(size_t)blockIdx.x*256 + t] = acc5 + f2_b[0];
    }
}

extern "C" void kernel_launch(void* const* d_in, const int* in_sizes, int n_in,
                              void* d_out, int out_size, void* d_ws, size_t ws_size,
                              hipStream_t stream){
    const float* agent_states = (const float*)d_in[0];
    const float* pos    = (const float*)d_in[1];
    const float* oneh   = (const float*)d_in[2];
    const float* pols   = (const float*)d_in[3];
    const float* acts   = (const float*)d_in[4];
    const float* w1     = (const float*)d_in[5];
    const float* b1     = (const float*)d_in[6];
    const float* w2     = (const float*)d_in[7];
    const float* b2     = (const float*)d_in[8];
    const float* se_w   = (const float*)d_in[9];
    const float* se_b   = (const float*)d_in[10];
    const float* key_w  = (const float*)d_in[11];
    const float* query_w= (const float*)d_in[13];
    const float* query_b= (const float*)d_in[14];
    const float* sap_w  = (const float*)d_in[15];
    const float* sap_b  = (const float*)d_in[16];
    const float* av_w   = (const float*)d_in[17];
    const float* av_b   = (const float*)d_in[18];
    const float* f1_w   = (const float*)d_in[19];
    const float* f1_b   = (const float*)d_in[20];
    const float* f2_w   = (const float*)d_in[21];
    const float* f2_b   = (const float*)d_in[22];

    unsigned* ws = (unsigned*)d_ws;
    unsigned* stA = ws + OFF_STA;
    unsigned* stP = ws + OFF_STP;

    float* value = (float*)d_out;
    float* wout  = value + (size_t)NB*NA*NA;

    kW<<<113, 256, 0, stream>>>(se_w, sap_w, av_w, f1_w, query_w, key_w, query_b, ws);
    k1_conv<<<BN/16, 256, 0, stream>>>(agent_states, pos, oneh, acts, pols,
                                       w1, b1, w2, b2, stA, stP);
    kA<<<BN/64, 256, 0, stream>>>(ws, se_b, wout);
    kB<<<BN/32, 256, 0, stream>>>(ws, sap_b, av_b, f1_b, f2_w, f2_b, wout, value);
}

// Round 4
// 94.068 us; speedup vs baseline: 2.2462x; 1.1672x over previous
//
#include <hip/hip_runtime.h>
#include <math.h>

#define NB 4096
#define NA 8
#define BN (NB*NA)   // 32768

// ws layout (u32 words)
#define OFF_SE   0            // se pack:  8 tiles * 512
#define OFF_SAP  4096         // sap pack: 8 tiles * 512
#define OFF_AV   8192         // av pack:  8 tiles * 1024
#define OFF_F1   16384        // f1 pack:  4 tiles * 1024
#define OFF_M    20480        // M pack:   8 tiles * 1024
#define OFF_U    28672        // u: 128 floats
#define OFF_W2T  28800        // conv2 w transposed [144][32] f32
#define OFF_STA  33408        // statesA pack: 2048 tiles * 512
#define OFF_STP  (33408+1048576)

typedef short short8 __attribute__((ext_vector_type(8)));
typedef float f32x4 __attribute__((ext_vector_type(4)));

#define MFMA(a,b,c) __builtin_amdgcn_mfma_f32_16x16x32_bf16(a,b,c,0,0,0)

__device__ __forceinline__ float fast_tanh(float x){
    float e = __expf(2.0f*x);
    return 1.0f - 2.0f*__builtin_amdgcn_rcpf(e+1.0f);
}
__device__ __forceinline__ unsigned bfr(float x){
    unsigned u = __float_as_uint(x);
    return (u + 0x7fffu + ((u>>16)&1u)) >> 16;
}
__device__ __forceinline__ unsigned pk2(float lo, float hi){
    return bfr(lo) | (bfr(hi)<<16);
}
__device__ __forceinline__ float bf2f(unsigned short s){
    return __uint_as_float(((unsigned)s)<<16);
}
__device__ __forceinline__ short8 fragld(const unsigned* p){
    union { uint4 u; short8 s; } cv;
    cv.u = *(const uint4*)p;
    return cv.s;
}

// ---------------- kW: pack all weights as A-fragments (pack16 of W^T), compute M, u, w2t ----
__global__ __launch_bounds__(256) void kW(const float* __restrict__ se_w,
        const float* __restrict__ sap_w, const float* __restrict__ av_w,
        const float* __restrict__ f1_w, const float* __restrict__ qw,
        const float* __restrict__ kw, const float* __restrict__ qb,
        const float* __restrict__ w2,
        unsigned* __restrict__ ws){
    int idx = blockIdx.x*256 + threadIdx.x;
    if (idx < 4096){                       // sePk (F=64 pad, rows f2=128)
        int w = idx, tile = w>>9, rem = w&511;
        int ft = rem>>6, r2 = (rem>>2)&15, wi = rem&3;
        int f2 = tile*16 + r2, f1 = ft*8 + wi*2;
        float lo = (f1   < 42)? se_w[f1*128+f2]     : 0.f;
        float hi = (f1+1 < 42)? se_w[(f1+1)*128+f2] : 0.f;
        ws[OFF_SE + w] = pk2(lo,hi);
    } else if (idx < 8192){                // sapPk (F=64 pad, limit 47)
        int w = idx-4096, tile = w>>9, rem = w&511;
        int ft = rem>>6, r2 = (rem>>2)&15, wi = rem&3;
        int f2 = tile*16 + r2, f1 = ft*8 + wi*2;
        float lo = (f1   < 47)? sap_w[f1*128+f2]     : 0.f;
        float hi = (f1+1 < 47)? sap_w[(f1+1)*128+f2] : 0.f;
        ws[OFF_SAP + w] = pk2(lo,hi);
    } else if (idx < 16384){               // avPk (F=128)
        int w = idx-8192, tile = w>>10, rem = w&1023;
        int ft = rem>>6, r2 = (rem>>2)&15, wi = rem&3;
        int f2 = tile*16 + r2, f1 = ft*8 + wi*2;
        ws[OFF_AV + w] = pk2(av_w[f1*128+f2], av_w[(f1+1)*128+f2]);
    } else if (idx < 20480){               // f1Pk (F=128, rows f2=64)
        int w = idx-16384, tile = w>>10, rem = w&1023;
        int ft = rem>>6, r2 = (rem>>2)&15, wi = rem&3;
        int f2 = tile*16 + r2, f1 = ft*8 + wi*2;
        ws[OFF_F1 + w] = pk2(f1_w[f1*64+f2], f1_w[(f1+1)*64+f2]);
    } else if (idx < 28672){               // MPk: M[e][f2] = qw[e]·kw[f2]
        int w = idx-20480, tile = w>>10, rem = w&1023;
        int ft = rem>>6, r2 = (rem>>2)&15, wi = rem&3;
        int f2 = tile*16 + r2, e0 = ft*8 + wi*2;
        float lo=0.f, hi=0.f;
        for (int d=0; d<128; ++d){
            float kv = kw[f2*128+d];
            lo += qw[e0*128+d]*kv;
            hi += qw[(e0+1)*128+d]*kv;
        }
        ws[OFF_M + w] = pk2(lo,hi);
    } else if (idx < 28800){               // u[f] = qb·kw[f]
        int f = idx-28672;
        float a = 0.f;
        for (int d=0; d<128; ++d) a += qb[d]*kw[f*128+d];
        ((float*)ws)[OFF_U + f] = a;
    } else if (idx < 33408){               // w2t[k][oc] = w2[oc][k]
        int w = idx-28800;
        int k = w>>5, oc = w&31;
        ((float*)ws)[OFF_W2T + w] = w2[oc*144 + k];
    }
}

// ---------------- k1: conv encoder -> statesA/statesP packs (16 agents = 1 tile per block) ---
__global__ __launch_bounds__(256) void k1_conv(const float* __restrict__ xin,
        const float* __restrict__ pos, const float* __restrict__ oneh,
        const float* __restrict__ acts, const float* __restrict__ pols,
        const float* __restrict__ w1, const float* __restrict__ b1,
        const float* __restrict__ b2,
        const float* __restrict__ wsW2T,
        unsigned* __restrict__ stA, unsigned* __restrict__ stP){
    __shared__ float s_in[16*76];     // 4864 B
    __shared__ float s_w1[432];
    __shared__ float s_b1[16];
    __shared__ float s_w2t[4608];     // 18432 B, [k][32]
    __shared__ float s_b2[32];
    __shared__ float s_h1[144*17];    // 9792 B, [k][agent] pad 17
    __shared__ float s_ap[160];       // [agent][act5|pol5]
    __shared__ float s_pose[160];     // [agent][pos2|oneh8]
    const int t = threadIdx.x;
    const int g0 = blockIdx.x*16;
    for (int q=t; q<1152; q+=256)
        *(float4*)&s_w2t[q*4] = *(const float4*)&wsW2T[q*4];
    for (int q=t; q<432; q+=256) s_w1[q] = w1[q];
    if (t<16) s_b1[t]=b1[t];
    if (t<32) s_b2[t]=b2[t];
    for (int q=t; q<1200; q+=256){
        int ag=q/75, r=q-ag*75;
        s_in[ag*76+r]=xin[(size_t)g0*75+q];
    }
    for (int q=t; q<160; q+=256){
        int ag=q/10, k=q-ag*10;
        s_ap[q]   = (k<5)? acts[(size_t)(g0+ag)*5+k] : pols[(size_t)(g0+ag)*5+(k-5)];
        s_pose[q] = (k<2)? pos[(size_t)(g0+ag)*2+k]  : oneh[(size_t)(g0+ag)*8+(k-2)];
    }
    __syncthreads();
    // conv1: thread = (ag = t&15, oc = t>>4); all-static register arrays
    {
        const int ag = t&15, oc = t>>4;
        float w[27];
        #pragma unroll
        for (int i=0;i<27;++i) w[i]=s_w1[oc*27+i];
        float out[9];
        float bb = s_b1[oc];
        #pragma unroll
        for (int p=0;p<9;++p) out[p]=bb;
        #pragma unroll
        for (int ic=0;ic<3;++ic){
            float pin[25];
            #pragma unroll
            for (int i=0;i<25;++i) pin[i]=s_in[ag*76+ic*25+i];
            #pragma unroll
            for (int y=0;y<3;++y)
              #pragma unroll
              for (int x=0;x<3;++x)
                #pragma unroll
                for (int ky=0;ky<3;++ky)
                  #pragma unroll
                  for (int kx=0;kx<3;++kx)
                    out[y*3+x] += pin[(y+ky)*5+(x+kx)] * w[ic*9+ky*3+kx];
        }
        #pragma unroll
        for (int p=0;p<9;++p){
            float v = out[p];
            v = (v>=0.f)? v : 0.01f*v;
            s_h1[(oc*9+p)*17 + ag] = v;
        }
    }
    __syncthreads();
    // conv2 + direct pack: thread = (ag = t>>4, oc pair = (t&15)*2)
    {
        const int ag = t>>4, o2 = t&15, oc = o2*2;
        float a0 = s_b2[oc], a1 = s_b2[oc+1];
        #pragma unroll 8
        for (int k=0;k<144;++k){
            float h = s_h1[k*17+ag];
            float2 wv = *(const float2*)&s_w2t[k*32+oc];
            a0 += h*wv.x; a1 += h*wv.y;
        }
        a0 = (a0>=0.f)? a0 : 0.01f*a0;
        a1 = (a1>=0.f)? a1 : 0.01f*a1;
        unsigned pw = pk2(a0,a1);
        size_t word = (size_t)blockIdx.x*512 + (o2>>2)*64 + ag*4 + (o2&3);
        stA[word]=pw; stP[word]=pw;
    }
    // pose/act/pol pack words (ft 4..7)
    {
        const int ft4 = t>>6, r = (t>>2)&15, wi = t&3;
        const int f0 = 32 + ft4*8 + wi*2;
        float a0=0.f,a1=0.f,p0=0.f,p1=0.f;
        if (f0 < 42){ a0 = s_pose[r*10 + f0-32]; p0 = a0; }
        else if (f0 < 47){ a0 = s_ap[r*10 + f0-42]; p0 = s_ap[r*10+5 + f0-42]; }
        if (f0+1 < 42){ a1 = s_pose[r*10 + f0-31]; p1 = a1; }
        else if (f0+1 < 47){ a1 = s_ap[r*10 + f0-41]; p1 = s_ap[r*10+5 + f0-41]; }
        size_t word = (size_t)blockIdx.x*512 + (4+ft4)*64 + r*4 + wi;
        stA[word]=pk2(a0,a1);
        stP[word]=pk2(p0,p1);
    }
}

// ---------------- kA: E = tanh(states@se+b); T = E@M+u; weight = softmax(T·E^T/sqrt128) -----
__global__ __launch_bounds__(256) void kA(const unsigned* __restrict__ ws,
        const float* __restrict__ se_b, float* __restrict__ wout){
    __shared__ unsigned sE[4096];   // 4 rowtiles * 1024 words
    __shared__ unsigned sT[4096];
    __shared__ float s_ub[256];     // u | se_b
    const int t = threadIdx.x;
    const int wv = t>>6, lane = t&63;
    const int g = lane>>4, c = lane&15;
    for (int q=t; q<256; q+=256) s_ub[q] = (q<128)? ((const float*)ws)[OFF_U+q] : se_b[q-128];
    __syncthreads();
    const int tile = blockIdx.x*4 + wv;
    const unsigned* stBase = ws + OFF_STA + (size_t)tile*512;
    // G1: E
    f32x4 acc[8];
    #pragma unroll
    for (int i=0;i<8;++i) acc[i] = (f32x4){0.f,0.f,0.f,0.f};
    #pragma unroll
    for (int kt=0; kt<2; ++kt){
        short8 bf = fragld(stBase + kt*256 + lane*4);
        #pragma unroll
        for (int ft=0; ft<8; ++ft){
            short8 af = fragld(ws + OFF_SE + ft*512 + kt*256 + lane*4);
            acc[ft] = MFMA(af, bf, acc[ft]);
        }
    }
    #pragma unroll
    for (int ft=0; ft<8; ++ft){
        const float* bp = &s_ub[128 + ft*16 + g*4];
        float d0 = fast_tanh(acc[ft][0]+bp[0]);
        float d1 = fast_tanh(acc[ft][1]+bp[1]);
        float d2 = fast_tanh(acc[ft][2]+bp[2]);
        float d3 = fast_tanh(acc[ft][3]+bp[3]);
        int word = wv*1024 + (2*ft + (g>>1))*64 + c*4 + (g&1)*2;
        *(uint2*)&sE[word] = make_uint2(pk2(d0,d1), pk2(d2,d3));
    }
    // G2: T = E@M + u
    f32x4 acc2[8];
    #pragma unroll
    for (int i=0;i<8;++i) acc2[i] = (f32x4){0.f,0.f,0.f,0.f};
    #pragma unroll
    for (int kt=0; kt<4; ++kt){
        short8 ef = fragld(&sE[wv*1024 + kt*256 + lane*4]);
        #pragma unroll
        for (int ft=0; ft<8; ++ft){
            short8 mf = fragld(ws + OFF_M + ft*1024 + kt*256 + lane*4);
            acc2[ft] = MFMA(mf, ef, acc2[ft]);
        }
    }
    #pragma unroll
    for (int ft=0; ft<8; ++ft){
        const float* up = &s_ub[ft*16 + g*4];
        int word = wv*1024 + (2*ft + (g>>1))*64 + c*4 + (g&1)*2;
        *(uint2*)&sT[word] = make_uint2(pk2(acc2[ft][0]+up[0], acc2[ft][1]+up[1]),
                                        pk2(acc2[ft][2]+up[2], acc2[ft][3]+up[3]));
    }
    // logits: L[a][j] = sum_d T[a][d] E[j][d]
    f32x4 L = (f32x4){0.f,0.f,0.f,0.f};
    #pragma unroll
    for (int kt=0; kt<4; ++kt){
        short8 tf = fragld(&sT[wv*1024 + kt*256 + lane*4]);
        short8 ef = fragld(&sE[wv*1024 + kt*256 + lane*4]);
        L = MFMA(tf, ef, L);
    }
    float sc[4];
    #pragma unroll
    for (int r=0;r<4;++r) sc[r] = L[r]*0.08838834764831845f;
    #pragma unroll
    for (int r=0;r<4;++r){
        float m = sc[r];
        m = fmaxf(m, __shfl_xor(m,1));
        m = fmaxf(m, __shfl_xor(m,2));
        m = fmaxf(m, __shfl_xor(m,4));
        float ex = __expf(sc[r]-m);
        float su = ex;
        su += __shfl_xor(su,1);
        su += __shfl_xor(su,2);
        su += __shfl_xor(su,4);
        sc[r] = ex/su;
    }
    if ((c>>3) == (g>>1)){
        int batch = tile*2 + (g>>1);
        int base = batch*64 + (c&7);
        #pragma unroll
        for (int r=0;r<4;++r)
            wout[base + ((g&1)*4 + r)*8] = sc[r];
    }
}

// ---------------- kB: SAP -> AV -> @f1 -> attention-mix -> value. 32 rows (4 batches)/block.
__global__ __launch_bounds__(256) void kB(const unsigned* __restrict__ ws,
        const float* __restrict__ sap_b, const float* __restrict__ av_b,
        const float* __restrict__ f1_b, const float* __restrict__ f2_w,
        const float* __restrict__ f2_b,
        const float* __restrict__ wout, float* __restrict__ value){
    __shared__ unsigned sSAP[4096];   // [v][rt][1024]
    __shared__ unsigned sAV[4096];
    __shared__ unsigned sA64[32*36];  // bf16 [row][72]
    __shared__ unsigned sP64[32*36];
    __shared__ float s_b64[32*68];
    __shared__ float s_w[256];
    __shared__ float s_bias[384];     // sap_b | av_b | f1_b | f2_w
    const int t = threadIdx.x;
    const int wv = t>>6, lane = t&63;
    const int g = lane>>4, c = lane&15;
    const int v = wv>>1, rt = wv&1;
    for (int q=t; q<384; q+=256)
        s_bias[q] = (q<128)? sap_b[q] : (q<256)? av_b[q-128] : (q<320)? f1_b[q-256] : f2_w[q-320];
    s_w[t] = wout[(size_t)blockIdx.x*256 + t];
    __syncthreads();
    const int tile = blockIdx.x*2 + rt;
    const unsigned* stBase = ws + (v? OFF_STP : OFF_STA) + (size_t)tile*512;
    unsigned* sapB = &sSAP[(v*2+rt)*1024];
    unsigned* avB  = &sAV[(v*2+rt)*1024];
    // G1: SAP = tanh(sap^T · x^T)
    f32x4 acc[8];
    #pragma unroll
    for (int i=0;i<8;++i) acc[i] = (f32x4){0.f,0.f,0.f,0.f};
    #pragma unroll
    for (int kt=0; kt<2; ++kt){
        short8 bf = fragld(stBase + kt*256 + lane*4);
        #pragma unroll
        for (int ft=0; ft<8; ++ft){
            short8 af = fragld(ws + OFF_SAP + ft*512 + kt*256 + lane*4);
            acc[ft] = MFMA(af, bf, acc[ft]);
        }
    }
    #pragma unroll
    for (int ft=0; ft<8; ++ft){
        const float* bp = &s_bias[ft*16 + g*4];
        float d0 = fast_tanh(acc[ft][0]+bp[0]);
        float d1 = fast_tanh(acc[ft][1]+bp[1]);
        float d2 = fast_tanh(acc[ft][2]+bp[2]);
        float d3 = fast_tanh(acc[ft][3]+bp[3]);
        int word = (2*ft + (g>>1))*64 + c*4 + (g&1)*2;
        *(uint2*)&sapB[word] = make_uint2(pk2(d0,d1), pk2(d2,d3));
    }
    // G2: AV = tanh(av^T · SAP^T)
    f32x4 acc2[8];
    #pragma unroll
    for (int i=0;i<8;++i) acc2[i] = (f32x4){0.f,0.f,0.f,0.f};
    #pragma unroll
    for (int kt=0; kt<4; ++kt){
        short8 bf = fragld(&sapB[kt*256 + lane*4]);
        #pragma unroll
        for (int ft=0; ft<8; ++ft){
            short8 af = fragld(ws + OFF_AV + ft*1024 + kt*256 + lane*4);
            acc2[ft] = MFMA(af, bf, acc2[ft]);
        }
    }
    #pragma unroll
    for (int ft=0; ft<8; ++ft){
        const float* bp = &s_bias[128 + ft*16 + g*4];
        float d0 = fast_tanh(acc2[ft][0]+bp[0]);
        float d1 = fast_tanh(acc2[ft][1]+bp[1]);
        float d2 = fast_tanh(acc2[ft][2]+bp[2]);
        float d3 = fast_tanh(acc2[ft][3]+bp[3]);
        int word = (2*ft + (g>>1))*64 + c*4 + (g&1)*2;
        *(uint2*)&avB[word] = make_uint2(pk2(d0,d1), pk2(d2,d3));
    }
    // G3: X64 = f1^T · AV^T  (64 cols)
    f32x4 acc3[4];
    #pragma unroll
    for (int i=0;i<4;++i) acc3[i] = (f32x4){0.f,0.f,0.f,0.f};
    #pragma unroll
    for (int kt=0; kt<4; ++kt){
        short8 bf = fragld(&avB[kt*256 + lane*4]);
        #pragma unroll
        for (int ft=0; ft<4; ++ft){
            short8 af = fragld(ws + OFF_F1 + ft*1024 + kt*256 + lane*4);
            acc3[ft] = MFMA(af, bf, acc3[ft]);
        }
    }
    {
        unsigned* dst = v? sP64 : sA64;
        int row = rt*16 + c;
        #pragma unroll
        for (int ft=0; ft<4; ++ft){
            int idx = row*36 + ft*8 + 2*g;
            *(uint2*)&dst[idx] = make_uint2(pk2(acc3[ft][0], acc3[ft][1]),
                                            pk2(acc3[ft][2], acc3[ft][3]));
        }
    }
    __syncthreads();
    // b64[bq][a][c] = sum_j w[bq,a,j] * A64[bq*8+j][c]
    const unsigned short* A16 = (const unsigned short*)sA64;
    const unsigned short* P16 = (const unsigned short*)sP64;
    #pragma unroll
    for (int k=0; k<8; ++k){
        int e = t + 256*k;
        int bq = e>>9, a = (e>>6)&7, cc = e&63;
        const float* wp = &s_w[bq*64 + a*8];
        float acc4 = 0.f;
        #pragma unroll
        for (int j=0;j<8;++j) acc4 += wp[j]*bf2f(A16[(bq*8+j)*72 + cc]);
        s_b64[(bq*8+a)*68 + cc] = acc4;
    }
    __syncthreads();
    {
        int bq = t>>6, a = (t>>3)&7, i = t&7;
        float w_ai = s_w[bq*64 + a*8 + i];
        const float* pb = &s_b64[(bq*8+a)*68];
        const unsigned short* pA = &A16[(bq*8+i)*72];
        const unsigned short* pP = &P16[(bq*8+i)*72];
        float acc5 = 0.f;
        #pragma unroll 8
        for (int cc=0; cc<64; ++cc){
            float dd = bf2f(pP[cc]) - bf2f(pA[cc]);
            acc5 += fast_tanh(pb[cc] + w_ai*dd + s_bias[256+cc]) * s_bias[320+cc];
        }
        value[(size_t)blockIdx.x*256 + t] = acc5 + f2_b[0];
    }
}

extern "C" void kernel_launch(void* const* d_in, const int* in_sizes, int n_in,
                              void* d_out, int out_size, void* d_ws, size_t ws_size,
                              hipStream_t stream){
    const float* agent_states = (const float*)d_in[0];
    const float* pos    = (const float*)d_in[1];
    const float* oneh   = (const float*)d_in[2];
    const float* pols   = (const float*)d_in[3];
    const float* acts   = (const float*)d_in[4];
    const float* w1     = (const float*)d_in[5];
    const float* b1     = (const float*)d_in[6];
    const float* w2     = (const float*)d_in[7];
    const float* b2     = (const float*)d_in[8];
    const float* se_w   = (const float*)d_in[9];
    const float* se_b   = (const float*)d_in[10];
    const float* key_w  = (const float*)d_in[11];
    const float* query_w= (const float*)d_in[13];
    const float* query_b= (const float*)d_in[14];
    const float* sap_w  = (const float*)d_in[15];
    const float* sap_b  = (const float*)d_in[16];
    const float* av_w   = (const float*)d_in[17];
    const float* av_b   = (const float*)d_in[18];
    const float* f1_w   = (const float*)d_in[19];
    const float* f1_b   = (const float*)d_in[20];
    const float* f2_w   = (const float*)d_in[21];
    const float* f2_b   = (const float*)d_in[22];

    unsigned* ws = (unsigned*)d_ws;
    unsigned* stA = ws + OFF_STA;
    unsigned* stP = ws + OFF_STP;

    float* value = (float*)d_out;
    float* wout  = value + (size_t)NB*NA*NA;

    kW<<<131, 256, 0, stream>>>(se_w, sap_w, av_w, f1_w, query_w, key_w, query_b, w2, ws);
    k1_conv<<<BN/16, 256, 0, stream>>>(agent_states, pos, oneh, acts, pols,
                                       w1, b1, b2, ((const float*)ws)+OFF_W2T, stA, stP);
    kA<<<BN/64, 256, 0, stream>>>(ws, se_b, wout);
    kB<<<BN/32, 256, 0, stream>>>(ws, sap_b, av_b, f1_b, f2_w, f2_b, wout, value);
}

// Round 5
// 71.150 us; speedup vs baseline: 2.9698x; 1.3221x over previous
//
#include <hip/hip_runtime.h>
#include <math.h>

#define NB 4096
#define NA 8
#define BN (NB*NA)   // 32768

// ws layout (u32 words)
#define OFF_SE   0            // se pack:  8 tiles * 512
#define OFF_SAP  4096         // sap pack: 8 tiles * 512
#define OFF_AV   8192         // av pack:  8 tiles * 1024
#define OFF_F1   16384        // f1 pack:  4 tiles * 1024
#define OFF_M    20480        // M pack:   8 tiles * 1024
#define OFF_U    28672        // u: 128 floats
#define OFF_W2T  28800        // conv2 w transposed [144][32] f32
#define OFF_STA  33408        // statesA pack: 2048 tiles * 512
#define OFF_STP  (33408+1048576)

typedef short short8 __attribute__((ext_vector_type(8)));
typedef float f32x4 __attribute__((ext_vector_type(4)));

#define MFMA(a,b,c) __builtin_amdgcn_mfma_f32_16x16x32_bf16(a,b,c,0,0,0)

__device__ __forceinline__ float fast_tanh(float x){
    float e = __expf(2.0f*x);
    return 1.0f - 2.0f*__builtin_amdgcn_rcpf(e+1.0f);
}
__device__ __forceinline__ unsigned bfr(float x){
    unsigned u = __float_as_uint(x);
    return (u + 0x7fffu + ((u>>16)&1u)) >> 16;
}
__device__ __forceinline__ unsigned pk2(float lo, float hi){
    return bfr(lo) | (bfr(hi)<<16);
}
__device__ __forceinline__ float bf2f(unsigned short s){
    return __uint_as_float(((unsigned)s)<<16);
}
__device__ __forceinline__ short8 fragld(const unsigned* p){
    union { uint4 u; short8 s; } cv;
    cv.u = *(const uint4*)p;
    return cv.s;
}

// ---------------- kW: pack all weights as A-fragments (pack16 of W^T), compute M, u, w2t ----
__global__ __launch_bounds__(256) void kW(const float* __restrict__ se_w,
        const float* __restrict__ sap_w, const float* __restrict__ av_w,
        const float* __restrict__ f1_w, const float* __restrict__ qw,
        const float* __restrict__ kw, const float* __restrict__ qb,
        const float* __restrict__ w2,
        unsigned* __restrict__ ws){
    int idx = blockIdx.x*256 + threadIdx.x;
    if (idx < 4096){                       // sePk (F=64 pad, rows f2=128)
        int w = idx, tile = w>>9, rem = w&511;
        int ft = rem>>6, r2 = (rem>>2)&15, wi = rem&3;
        int f2 = tile*16 + r2, f1 = ft*8 + wi*2;
        float lo = (f1   < 42)? se_w[f1*128+f2]     : 0.f;
        float hi = (f1+1 < 42)? se_w[(f1+1)*128+f2] : 0.f;
        ws[OFF_SE + w] = pk2(lo,hi);
    } else if (idx < 8192){                // sapPk (F=64 pad, limit 47)
        int w = idx-4096, tile = w>>9, rem = w&511;
        int ft = rem>>6, r2 = (rem>>2)&15, wi = rem&3;
        int f2 = tile*16 + r2, f1 = ft*8 + wi*2;
        float lo = (f1   < 47)? sap_w[f1*128+f2]     : 0.f;
        float hi = (f1+1 < 47)? sap_w[(f1+1)*128+f2] : 0.f;
        ws[OFF_SAP + w] = pk2(lo,hi);
    } else if (idx < 16384){               // avPk (F=128)
        int w = idx-8192, tile = w>>10, rem = w&1023;
        int ft = rem>>6, r2 = (rem>>2)&15, wi = rem&3;
        int f2 = tile*16 + r2, f1 = ft*8 + wi*2;
        ws[OFF_AV + w] = pk2(av_w[f1*128+f2], av_w[(f1+1)*128+f2]);
    } else if (idx < 20480){               // f1Pk (F=128, rows f2=64)
        int w = idx-16384, tile = w>>10, rem = w&1023;
        int ft = rem>>6, r2 = (rem>>2)&15, wi = rem&3;
        int f2 = tile*16 + r2, f1 = ft*8 + wi*2;
        ws[OFF_F1 + w] = pk2(f1_w[f1*64+f2], f1_w[(f1+1)*64+f2]);
    } else if (idx < 28672){               // MPk: M[e][f2] = qw[e]·kw[f2]
        int w = idx-20480, tile = w>>10, rem = w&1023;
        int ft = rem>>6, r2 = (rem>>2)&15, wi = rem&3;
        int f2 = tile*16 + r2, e0 = ft*8 + wi*2;
        float lo=0.f, hi=0.f;
        for (int d=0; d<128; ++d){
            float kv = kw[f2*128+d];
            lo += qw[e0*128+d]*kv;
            hi += qw[(e0+1)*128+d]*kv;
        }
        ws[OFF_M + w] = pk2(lo,hi);
    } else if (idx < 28800){               // u[f] = qb·kw[f]
        int f = idx-28672;
        float a = 0.f;
        for (int d=0; d<128; ++d) a += qb[d]*kw[f*128+d];
        ((float*)ws)[OFF_U + f] = a;
    } else if (idx < 33408){               // w2t[k][oc] = w2[oc][k]
        int w = idx-28800;
        int k = w>>5, oc = w&31;
        ((float*)ws)[OFF_W2T + w] = w2[oc*144 + k];
    }
}

// ---------------- k1: conv encoder -> statesA/statesP packs (16 agents = 1 tile per block) ---
__global__ __launch_bounds__(256) void k1_conv(const float* __restrict__ xin,
        const float* __restrict__ pos, const float* __restrict__ oneh,
        const float* __restrict__ acts, const float* __restrict__ pols,
        const float* __restrict__ w1, const float* __restrict__ b1,
        const float* __restrict__ b2,
        const float* __restrict__ wsW2T,
        unsigned* __restrict__ stA, unsigned* __restrict__ stP){
    __shared__ float s_in[16*76];     // 4864 B
    __shared__ float s_w1[432];
    __shared__ float s_b1[16];
    __shared__ float s_w2t[4608];     // 18432 B, [k][32]
    __shared__ float s_b2[32];
    __shared__ float s_h1[144*17];    // 9792 B, [k][agent] pad 17
    __shared__ float s_ap[160];       // [agent][act5|pol5]
    __shared__ float s_pose[160];     // [agent][pos2|oneh8]
    const int t = threadIdx.x;
    const int g0 = blockIdx.x*16;
    for (int q=t; q<1152; q+=256)
        *(float4*)&s_w2t[q*4] = *(const float4*)&wsW2T[q*4];
    for (int q=t; q<432; q+=256) s_w1[q] = w1[q];
    if (t<16) s_b1[t]=b1[t];
    if (t<32) s_b2[t]=b2[t];
    for (int q=t; q<1200; q+=256){
        int ag=q/75, r=q-ag*75;
        s_in[ag*76+r]=xin[(size_t)g0*75+q];
    }
    for (int q=t; q<160; q+=256){
        int ag=q/10, k=q-ag*10;
        s_ap[q]   = (k<5)? acts[(size_t)(g0+ag)*5+k] : pols[(size_t)(g0+ag)*5+(k-5)];
        s_pose[q] = (k<2)? pos[(size_t)(g0+ag)*2+k]  : oneh[(size_t)(g0+ag)*8+(k-2)];
    }
    __syncthreads();
    // conv1: thread = (ag = t&15, oc = t>>4); all-static register arrays
    {
        const int ag = t&15, oc = t>>4;
        float w[27];
        #pragma unroll
        for (int i=0;i<27;++i) w[i]=s_w1[oc*27+i];
        float out[9];
        float bb = s_b1[oc];
        #pragma unroll
        for (int p=0;p<9;++p) out[p]=bb;
        #pragma unroll
        for (int ic=0;ic<3;++ic){
            float pin[25];
            #pragma unroll
            for (int i=0;i<25;++i) pin[i]=s_in[ag*76+ic*25+i];
            #pragma unroll
            for (int y=0;y<3;++y)
              #pragma unroll
              for (int x=0;x<3;++x)
                #pragma unroll
                for (int ky=0;ky<3;++ky)
                  #pragma unroll
                  for (int kx=0;kx<3;++kx)
                    out[y*3+x] += pin[(y+ky)*5+(x+kx)] * w[ic*9+ky*3+kx];
        }
        #pragma unroll
        for (int p=0;p<9;++p){
            float v = out[p];
            v = (v>=0.f)? v : 0.01f*v;
            s_h1[(oc*9+p)*17 + ag] = v;
        }
    }
    __syncthreads();
    // conv2 + direct pack: thread = (ag = t>>4, oc pair = (t&15)*2)
    {
        const int ag = t>>4, o2 = t&15, oc = o2*2;
        float a0 = s_b2[oc], a1 = s_b2[oc+1];
        #pragma unroll 8
        for (int k=0;k<144;++k){
            float h = s_h1[k*17+ag];
            float2 wv = *(const float2*)&s_w2t[k*32+oc];
            a0 += h*wv.x; a1 += h*wv.y;
        }
        a0 = (a0>=0.f)? a0 : 0.01f*a0;
        a1 = (a1>=0.f)? a1 : 0.01f*a1;
        unsigned pw = pk2(a0,a1);
        size_t word = (size_t)blockIdx.x*512 + (o2>>2)*64 + ag*4 + (o2&3);
        stA[word]=pw; stP[word]=pw;
    }
    // pose/act/pol pack words (ft 4..7)
    {
        const int ft4 = t>>6, r = (t>>2)&15, wi = t&3;
        const int f0 = 32 + ft4*8 + wi*2;
        float a0=0.f,a1=0.f,p0=0.f,p1=0.f;
        if (f0 < 42){ a0 = s_pose[r*10 + f0-32]; p0 = a0; }
        else if (f0 < 47){ a0 = s_ap[r*10 + f0-42]; p0 = s_ap[r*10+5 + f0-42]; }
        if (f0+1 < 42){ a1 = s_pose[r*10 + f0-31]; p1 = a1; }
        else if (f0+1 < 47){ a1 = s_ap[r*10 + f0-41]; p1 = s_ap[r*10+5 + f0-41]; }
        size_t word = (size_t)blockIdx.x*512 + (4+ft4)*64 + r*4 + wi;
        stA[word]=pk2(a0,a1);
        stP[word]=pk2(p0,p1);
    }
}

// ---------------- kA: E; T = E@M+u; weight = softmax(T·E^T/sqrt128) -----
// 128 threads = 2 waves; each wave handles 2 row tiles (R=2 weight-frag reuse).
__global__ __launch_bounds__(128,2) void kA(const unsigned* __restrict__ ws,
        const float* __restrict__ se_b, float* __restrict__ wout){
    __shared__ unsigned sE[4096];   // 4 rowtiles * 1024 words
    __shared__ unsigned sT[4096];
    __shared__ float s_ub[256];     // u | se_b
    const int t = threadIdx.x;
    const int wv = t>>6, lane = t&63;
    const int g = lane>>4, c = lane&15;
    for (int q=t; q<256; q+=128) s_ub[q] = (q<128)? ((const float*)ws)[OFF_U+q] : se_b[q-128];
    __syncthreads();
    const int tile0 = blockIdx.x*4 + wv*2;
    const unsigned* stBase = ws + OFF_STA + (size_t)tile0*512;
    unsigned* eB = &sE[wv*2048];
    unsigned* tB = &sT[wv*2048];
    // G1: E = tanh(states@se + b)
    f32x4 acc[2][8];
    #pragma unroll
    for (int r=0;r<2;++r)
      #pragma unroll
      for (int i=0;i<8;++i) acc[r][i] = (f32x4){0.f,0.f,0.f,0.f};
    #pragma unroll
    for (int kt=0; kt<2; ++kt){
        short8 bf0 = fragld(stBase + kt*256 + lane*4);
        short8 bf1 = fragld(stBase + 512 + kt*256 + lane*4);
        #pragma unroll
        for (int ft=0; ft<8; ++ft){
            short8 af = fragld(ws + OFF_SE + ft*512 + kt*256 + lane*4);
            acc[0][ft] = MFMA(af, bf0, acc[0][ft]);
            acc[1][ft] = MFMA(af, bf1, acc[1][ft]);
        }
    }
    #pragma unroll
    for (int r=0;r<2;++r)
      #pragma unroll
      for (int ft=0; ft<8; ++ft){
        const float* bp = &s_ub[128 + ft*16 + g*4];
        float d0 = fast_tanh(acc[r][ft][0]+bp[0]);
        float d1 = fast_tanh(acc[r][ft][1]+bp[1]);
        float d2 = fast_tanh(acc[r][ft][2]+bp[2]);
        float d3 = fast_tanh(acc[r][ft][3]+bp[3]);
        int word = r*1024 + (2*ft + (g>>1))*64 + c*4 + (g&1)*2;
        *(uint2*)&eB[word] = make_uint2(pk2(d0,d1), pk2(d2,d3));
      }
    // G2: T = E@M + u
    f32x4 acc2[2][8];
    #pragma unroll
    for (int r=0;r<2;++r)
      #pragma unroll
      for (int i=0;i<8;++i) acc2[r][i] = (f32x4){0.f,0.f,0.f,0.f};
    #pragma unroll
    for (int kt=0; kt<4; ++kt){
        short8 ef0 = fragld(&eB[kt*256 + lane*4]);
        short8 ef1 = fragld(&eB[1024 + kt*256 + lane*4]);
        #pragma unroll
        for (int ft=0; ft<8; ++ft){
            short8 mf = fragld(ws + OFF_M + ft*1024 + kt*256 + lane*4);
            acc2[0][ft] = MFMA(mf, ef0, acc2[0][ft]);
            acc2[1][ft] = MFMA(mf, ef1, acc2[1][ft]);
        }
    }
    #pragma unroll
    for (int r=0;r<2;++r)
      #pragma unroll
      for (int ft=0; ft<8; ++ft){
        const float* up = &s_ub[ft*16 + g*4];
        int word = r*1024 + (2*ft + (g>>1))*64 + c*4 + (g&1)*2;
        *(uint2*)&tB[word] = make_uint2(pk2(acc2[r][ft][0]+up[0], acc2[r][ft][1]+up[1]),
                                        pk2(acc2[r][ft][2]+up[2], acc2[r][ft][3]+up[3]));
      }
    // logits + softmax + wout, per r
    #pragma unroll
    for (int r=0;r<2;++r){
        f32x4 L = (f32x4){0.f,0.f,0.f,0.f};
        #pragma unroll
        for (int kt=0; kt<4; ++kt){
            short8 tf = fragld(&tB[r*1024 + kt*256 + lane*4]);
            short8 ef = fragld(&eB[r*1024 + kt*256 + lane*4]);
            L = MFMA(tf, ef, L);
        }
        float sc[4];
        #pragma unroll
        for (int q=0;q<4;++q) sc[q] = L[q]*0.08838834764831845f;
        #pragma unroll
        for (int q=0;q<4;++q){
            float m = sc[q];
            m = fmaxf(m, __shfl_xor(m,1));
            m = fmaxf(m, __shfl_xor(m,2));
            m = fmaxf(m, __shfl_xor(m,4));
            float ex = __expf(sc[q]-m);
            float su = ex;
            su += __shfl_xor(su,1);
            su += __shfl_xor(su,2);
            su += __shfl_xor(su,4);
            sc[q] = ex/su;
        }
        if ((c>>3) == (g>>1)){
            int batch = (tile0+r)*2 + (g>>1);
            int base = batch*64 + (c&7);
            #pragma unroll
            for (int q=0;q<4;++q)
                wout[base + ((g&1)*4 + q)*8] = sc[q];
        }
    }
}

// ---------------- kB: SAP -> AV -> @f1 -> attention-mix -> value.
// 256 threads = 4 waves; wave = 1 tile, computes BOTH variants (weights shared in regs).
// Block = 4 tiles = 64 rows = 8 batches.
__global__ __launch_bounds__(256,2) void kB(const unsigned* __restrict__ ws,
        const float* __restrict__ sap_b, const float* __restrict__ av_b,
        const float* __restrict__ f1_b, const float* __restrict__ f2_w,
        const float* __restrict__ f2_b,
        const float* __restrict__ wout, float* __restrict__ value){
    __shared__ unsigned s_buf[8192];  // [tile][v][1024], SAP then AV in place
    __shared__ unsigned sA64[64*36];  // bf16 [row][72]
    __shared__ unsigned sP64[64*36];
    __shared__ float s_b64[64*68];
    __shared__ float s_w[512];
    __shared__ float s_bias[384];     // sap_b | av_b | f1_b | f2_w
    const int t = threadIdx.x;
    const int wv = t>>6, lane = t&63;
    const int g = lane>>4, c = lane&15;
    for (int q=t; q<384; q+=256)
        s_bias[q] = (q<128)? sap_b[q] : (q<256)? av_b[q-128] : (q<320)? f1_b[q-256] : f2_w[q-320];
    for (int q=t; q<512; q+=256) s_w[q] = wout[(size_t)blockIdx.x*512 + q];
    __syncthreads();
    const int tile = blockIdx.x*4 + wv;
    const unsigned* stA = ws + OFF_STA + (size_t)tile*512;
    const unsigned* stP = ws + OFF_STP + (size_t)tile*512;
    unsigned* bufA = &s_buf[wv*2048];
    unsigned* bufP = &s_buf[wv*2048 + 1024];
    // G1: SAP = tanh(sap^T · x^T), both variants with shared weight frags
    f32x4 acc[2][8];
    #pragma unroll
    for (int v=0;v<2;++v)
      #pragma unroll
      for (int i=0;i<8;++i) acc[v][i] = (f32x4){0.f,0.f,0.f,0.f};
    #pragma unroll
    for (int kt=0; kt<2; ++kt){
        short8 bfA = fragld(stA + kt*256 + lane*4);
        short8 bfP = fragld(stP + kt*256 + lane*4);
        #pragma unroll
        for (int ft=0; ft<8; ++ft){
            short8 af = fragld(ws + OFF_SAP + ft*512 + kt*256 + lane*4);
            acc[0][ft] = MFMA(af, bfA, acc[0][ft]);
            acc[1][ft] = MFMA(af, bfP, acc[1][ft]);
        }
    }
    #pragma unroll
    for (int v=0;v<2;++v){
        unsigned* dst = v? bufP : bufA;
        #pragma unroll
        for (int ft=0; ft<8; ++ft){
            const float* bp = &s_bias[ft*16 + g*4];
            float d0 = fast_tanh(acc[v][ft][0]+bp[0]);
            float d1 = fast_tanh(acc[v][ft][1]+bp[1]);
            float d2 = fast_tanh(acc[v][ft][2]+bp[2]);
            float d3 = fast_tanh(acc[v][ft][3]+bp[3]);
            int word = (2*ft + (g>>1))*64 + c*4 + (g&1)*2;
            *(uint2*)&dst[word] = make_uint2(pk2(d0,d1), pk2(d2,d3));
        }
    }
    // G2: AV = tanh(av^T · SAP^T)
    f32x4 acc2[2][8];
    #pragma unroll
    for (int v=0;v<2;++v)
      #pragma unroll
      for (int i=0;i<8;++i) acc2[v][i] = (f32x4){0.f,0.f,0.f,0.f};
    #pragma unroll
    for (int kt=0; kt<4; ++kt){
        short8 bfA = fragld(&bufA[kt*256 + lane*4]);
        short8 bfP = fragld(&bufP[kt*256 + lane*4]);
        #pragma unroll
        for (int ft=0; ft<8; ++ft){
            short8 af = fragld(ws + OFF_AV + ft*1024 + kt*256 + lane*4);
            acc2[0][ft] = MFMA(af, bfA, acc2[0][ft]);
            acc2[1][ft] = MFMA(af, bfP, acc2[1][ft]);
        }
    }
    #pragma unroll
    for (int v=0;v<2;++v){
        unsigned* dst = v? bufP : bufA;   // overwrite own region (all reads done)
        #pragma unroll
        for (int ft=0; ft<8; ++ft){
            const float* bp = &s_bias[128 + ft*16 + g*4];
            float d0 = fast_tanh(acc2[v][ft][0]+bp[0]);
            float d1 = fast_tanh(acc2[v][ft][1]+bp[1]);
            float d2 = fast_tanh(acc2[v][ft][2]+bp[2]);
            float d3 = fast_tanh(acc2[v][ft][3]+bp[3]);
            int word = (2*ft + (g>>1))*64 + c*4 + (g&1)*2;
            *(uint2*)&dst[word] = make_uint2(pk2(d0,d1), pk2(d2,d3));
        }
    }
    // G3: X64 = f1^T · AV^T  (64 cols)
    f32x4 acc3[2][4];
    #pragma unroll
    for (int v=0;v<2;++v)
      #pragma unroll
      for (int i=0;i<4;++i) acc3[v][i] = (f32x4){0.f,0.f,0.f,0.f};
    #pragma unroll
    for (int kt=0; kt<4; ++kt){
        short8 bfA = fragld(&bufA[kt*256 + lane*4]);
        short8 bfP = fragld(&bufP[kt*256 + lane*4]);
        #pragma unroll
        for (int ft=0; ft<4; ++ft){
            short8 af = fragld(ws + OFF_F1 + ft*1024 + kt*256 + lane*4);
            acc3[0][ft] = MFMA(af, bfA, acc3[0][ft]);
            acc3[1][ft] = MFMA(af, bfP, acc3[1][ft]);
        }
    }
    {
        int row = wv*16 + c;
        #pragma unroll
        for (int v=0;v<2;++v){
            unsigned* dst = v? sP64 : sA64;
            #pragma unroll
            for (int ft=0; ft<4; ++ft){
                int idx = row*36 + ft*8 + 2*g;
                *(uint2*)&dst[idx] = make_uint2(pk2(acc3[v][ft][0], acc3[v][ft][1]),
                                                pk2(acc3[v][ft][2], acc3[v][ft][3]));
            }
        }
    }
    __syncthreads();
    // b64[bq][a][c] = sum_j w[bq,a,j] * A64[bq*8+j][c]   (8 batches)
    const unsigned short* A16 = (const unsigned short*)sA64;
    const unsigned short* P16 = (const unsigned short*)sP64;
    #pragma unroll
    for (int k=0; k<16; ++k){
        int e = t + 256*k;
        int bq = e>>9, a = (e>>6)&7, cc = e&63;
        const float* wp = &s_w[bq*64 + a*8];
        float acc4 = 0.f;
        #pragma unroll
        for (int j=0;j<8;++j) acc4 += wp[j]*bf2f(A16[(bq*8+j)*72 + cc]);
        s_b64[(bq*8+a)*68 + cc] = acc4;
    }
    __syncthreads();
    #pragma unroll
    for (int k=0; k<2; ++k){
        int o = t + 256*k;
        int bq = o>>6, a = (o>>3)&7, i = o&7;
        float w_ai = s_w[bq*64 + a*8 + i];
        const float* pb = &s_b64[(bq*8+a)*68];
        const unsigned short* pA = &A16[(bq*8+i)*72];
        const unsigned short* pP = &P16[(bq*8+i)*72];
        float acc5 = 0.f;
        #pragma unroll 8
        for (int cc=0; cc<64; ++cc){
            float dd = bf2f(pP[cc]) - bf2f(pA[cc]);
            acc5 += fast_tanh(pb[cc] + w_ai*dd + s_bias[256+cc]) * s_bias[320+cc];
        }
        value[(size_t)blockIdx.x*512 + o] = acc5 + f2_b[0];
    }
}

extern "C" void kernel_launch(void* const* d_in, const int* in_sizes, int n_in,
                              void* d_out, int out_size, void* d_ws, size_t ws_size,
                              hipStream_t stream){
    const float* agent_states = (const float*)d_in[0];
    const float* pos    = (const float*)d_in[1];
    const float* oneh   = (const float*)d_in[2];
    const float* pols   = (const float*)d_in[3];
    const float* acts   = (const float*)d_in[4];
    const float* w1     = (const float*)d_in[5];
    const float* b1     = (const float*)d_in[6];
    const float* w2     = (const float*)d_in[7];
    const float* b2     = (const float*)d_in[8];
    const float* se_w   = (const float*)d_in[9];
    const float* se_b   = (const float*)d_in[10];
    const float* key_w  = (const float*)d_in[11];
    const float* query_w= (const float*)d_in[13];
    const float* query_b= (const float*)d_in[14];
    const float* sap_w  = (const float*)d_in[15];
    const float* sap_b  = (const float*)d_in[16];
    const float* av_w   = (const float*)d_in[17];
    const float* av_b   = (const float*)d_in[18];
    const float* f1_w   = (const float*)d_in[19];
    const float* f1_b   = (const float*)d_in[20];
    const float* f2_w   = (const float*)d_in[21];
    const float* f2_b   = (const float*)d_in[22];

    unsigned* ws = (unsigned*)d_ws;
    unsigned* stA = ws + OFF_STA;
    unsigned* stP = ws + OFF_STP;

    float* value = (float*)d_out;
    float* wout  = value + (size_t)NB*NA*NA;

    kW<<<131, 256, 0, stream>>>(se_w, sap_w, av_w, f1_w, query_w, key_w, query_b, w2, ws);
    k1_conv<<<BN/16, 256, 0, stream>>>(agent_states, pos, oneh, acts, pols,
                                       w1, b1, b2, ((const float*)ws)+OFF_W2T, stA, stP);
    kA<<<BN/64, 128, 0, stream>>>(ws, se_b, wout);
    kB<<<BN/64, 256, 0, stream>>>(ws, sap_b, av_b, f1_b, f2_w, f2_b, wout, value);
}

// Round 6
// 67.980 us; speedup vs baseline: 3.1082x; 1.0466x over previous
//
#include <hip/hip_runtime.h>
#include <math.h>

#define NB 4096
#define NA 8
#define BN (NB*NA)   // 32768

// ws layout (u32 words)
#define OFF_SE   0            // se pack:  8 tiles * 512
#define OFF_SAP  4096         // sap pack: 8 tiles * 512
#define OFF_AV   8192         // av pack:  8 tiles * 1024
#define OFF_F1   16384        // f1 pack:  4 tiles * 1024
#define OFF_M    20480        // M pack:   8 tiles * 1024
#define OFF_U    28672        // u: 128 floats
#define OFF_W2T  28800        // conv2 w transposed [144][32] f32
#define OFF_STA  33408        // statesA pack: 2048 tiles * 512
#define OFF_STP  (33408+1048576)

typedef short short8 __attribute__((ext_vector_type(8)));
typedef float f32x4 __attribute__((ext_vector_type(4)));

#define MFMA(a,b,c) __builtin_amdgcn_mfma_f32_16x16x32_bf16(a,b,c,0,0,0)

__device__ __forceinline__ float fast_tanh(float x){
    float e = __expf(2.0f*x);
    return 1.0f - 2.0f*__builtin_amdgcn_rcpf(e+1.0f);
}
__device__ __forceinline__ unsigned bfr(float x){
    unsigned u = __float_as_uint(x);
    return (u + 0x7fffu + ((u>>16)&1u)) >> 16;
}
__device__ __forceinline__ unsigned pk2(float lo, float hi){
    return bfr(lo) | (bfr(hi)<<16);
}
__device__ __forceinline__ float bf2f(unsigned short s){
    return __uint_as_float(((unsigned)s)<<16);
}
__device__ __forceinline__ short8 fragld(const unsigned* p){
    union { uint4 u; short8 s; } cv;
    cv.u = *(const uint4*)p;
    return cv.s;
}

// ---------------- kW: pack all weights as A-fragments (pack16 of W^T), compute M, u, w2t ----
__global__ __launch_bounds__(256) void kW(const float* __restrict__ se_w,
        const float* __restrict__ sap_w, const float* __restrict__ av_w,
        const float* __restrict__ f1_w, const float* __restrict__ qw,
        const float* __restrict__ kw, const float* __restrict__ qb,
        const float* __restrict__ w2,
        unsigned* __restrict__ ws){
    int idx = blockIdx.x*256 + threadIdx.x;
    if (idx < 4096){                       // sePk (F=64 pad, rows f2=128)
        int w = idx, tile = w>>9, rem = w&511;
        int ft = rem>>6, r2 = (rem>>2)&15, wi = rem&3;
        int f2 = tile*16 + r2, f1 = ft*8 + wi*2;
        float lo = (f1   < 42)? se_w[f1*128+f2]     : 0.f;
        float hi = (f1+1 < 42)? se_w[(f1+1)*128+f2] : 0.f;
        ws[OFF_SE + w] = pk2(lo,hi);
    } else if (idx < 8192){                // sapPk (F=64 pad, limit 47)
        int w = idx-4096, tile = w>>9, rem = w&511;
        int ft = rem>>6, r2 = (rem>>2)&15, wi = rem&3;
        int f2 = tile*16 + r2, f1 = ft*8 + wi*2;
        float lo = (f1   < 47)? sap_w[f1*128+f2]     : 0.f;
        float hi = (f1+1 < 47)? sap_w[(f1+1)*128+f2] : 0.f;
        ws[OFF_SAP + w] = pk2(lo,hi);
    } else if (idx < 16384){               // avPk (F=128)
        int w = idx-8192, tile = w>>10, rem = w&1023;
        int ft = rem>>6, r2 = (rem>>2)&15, wi = rem&3;
        int f2 = tile*16 + r2, f1 = ft*8 + wi*2;
        ws[OFF_AV + w] = pk2(av_w[f1*128+f2], av_w[(f1+1)*128+f2]);
    } else if (idx < 20480){               // f1Pk (F=128, rows f2=64)
        int w = idx-16384, tile = w>>10, rem = w&1023;
        int ft = rem>>6, r2 = (rem>>2)&15, wi = rem&3;
        int f2 = tile*16 + r2, f1 = ft*8 + wi*2;
        ws[OFF_F1 + w] = pk2(f1_w[f1*64+f2], f1_w[(f1+1)*64+f2]);
    } else if (idx < 28672){               // MPk: M[e][f2] = qw[e]·kw[f2]
        int w = idx-20480, tile = w>>10, rem = w&1023;
        int ft = rem>>6, r2 = (rem>>2)&15, wi = rem&3;
        int f2 = tile*16 + r2, e0 = ft*8 + wi*2;
        float lo=0.f, hi=0.f;
        for (int d=0; d<128; ++d){
            float kv = kw[f2*128+d];
            lo += qw[e0*128+d]*kv;
            hi += qw[(e0+1)*128+d]*kv;
        }
        ws[OFF_M + w] = pk2(lo,hi);
    } else if (idx < 28800){               // u[f] = qb·kw[f]
        int f = idx-28672;
        float a = 0.f;
        for (int d=0; d<128; ++d) a += qb[d]*kw[f*128+d];
        ((float*)ws)[OFF_U + f] = a;
    } else if (idx < 33408){               // w2t[k][oc] = w2[oc][k]
        int w = idx-28800;
        int k = w>>5, oc = w&31;
        ((float*)ws)[OFF_W2T + w] = w2[oc*144 + k];
    }
}

// ---------------- k1: conv encoder -> statesA/statesP packs (16 agents = 1 tile per block) ---
__global__ __launch_bounds__(256) void k1_conv(const float* __restrict__ xin,
        const float* __restrict__ pos, const float* __restrict__ oneh,
        const float* __restrict__ acts, const float* __restrict__ pols,
        const float* __restrict__ w1, const float* __restrict__ b1,
        const float* __restrict__ b2,
        const float* __restrict__ wsW2T,
        unsigned* __restrict__ stA, unsigned* __restrict__ stP){
    __shared__ float s_in[16*76];     // 4864 B
    __shared__ float s_w1[432];
    __shared__ float s_b1[16];
    __shared__ float s_w2t[4608];     // 18432 B, [k][32]
    __shared__ float s_b2[32];
    __shared__ float s_h1[144*17];    // 9792 B, [k][agent] pad 17
    __shared__ float s_ap[160];       // [agent][act5|pol5]
    __shared__ float s_pose[160];     // [agent][pos2|oneh8]
    const int t = threadIdx.x;
    const int g0 = blockIdx.x*16;
    for (int q=t; q<1152; q+=256)
        *(float4*)&s_w2t[q*4] = *(const float4*)&wsW2T[q*4];
    for (int q=t; q<432; q+=256) s_w1[q] = w1[q];
    if (t<16) s_b1[t]=b1[t];
    if (t<32) s_b2[t]=b2[t];
    for (int q=t; q<1200; q+=256){
        int ag=q/75, r=q-ag*75;
        s_in[ag*76+r]=xin[(size_t)g0*75+q];
    }
    for (int q=t; q<160; q+=256){
        int ag=q/10, k=q-ag*10;
        s_ap[q]   = (k<5)? acts[(size_t)(g0+ag)*5+k] : pols[(size_t)(g0+ag)*5+(k-5)];
        s_pose[q] = (k<2)? pos[(size_t)(g0+ag)*2+k]  : oneh[(size_t)(g0+ag)*8+(k-2)];
    }
    __syncthreads();
    // conv1: thread = (ag = t&15, oc = t>>4); all-static register arrays
    {
        const int ag = t&15, oc = t>>4;
        float w[27];
        #pragma unroll
        for (int i=0;i<27;++i) w[i]=s_w1[oc*27+i];
        float out[9];
        float bb = s_b1[oc];
        #pragma unroll
        for (int p=0;p<9;++p) out[p]=bb;
        #pragma unroll
        for (int ic=0;ic<3;++ic){
            float pin[25];
            #pragma unroll
            for (int i=0;i<25;++i) pin[i]=s_in[ag*76+ic*25+i];
            #pragma unroll
            for (int y=0;y<3;++y)
              #pragma unroll
              for (int x=0;x<3;++x)
                #pragma unroll
                for (int ky=0;ky<3;++ky)
                  #pragma unroll
                  for (int kx=0;kx<3;++kx)
                    out[y*3+x] += pin[(y+ky)*5+(x+kx)] * w[ic*9+ky*3+kx];
        }
        #pragma unroll
        for (int p=0;p<9;++p){
            float v = out[p];
            v = (v>=0.f)? v : 0.01f*v;
            s_h1[(oc*9+p)*17 + ag] = v;
        }
    }
    __syncthreads();
    // conv2 + direct pack: thread = (ag = t>>4, oc pair = (t&15)*2)
    {
        const int ag = t>>4, o2 = t&15, oc = o2*2;
        float a0 = s_b2[oc], a1 = s_b2[oc+1];
        #pragma unroll 8
        for (int k=0;k<144;++k){
            float h = s_h1[k*17+ag];
            float2 wv = *(const float2*)&s_w2t[k*32+oc];
            a0 += h*wv.x; a1 += h*wv.y;
        }
        a0 = (a0>=0.f)? a0 : 0.01f*a0;
        a1 = (a1>=0.f)? a1 : 0.01f*a1;
        unsigned pw = pk2(a0,a1);
        size_t word = (size_t)blockIdx.x*512 + (o2>>2)*64 + ag*4 + (o2&3);
        stA[word]=pw; stP[word]=pw;
    }
    // pose/act/pol pack words (ft 4..7)
    {
        const int ft4 = t>>6, r = (t>>2)&15, wi = t&3;
        const int f0 = 32 + ft4*8 + wi*2;
        float a0=0.f,a1=0.f,p0=0.f,p1=0.f;
        if (f0 < 42){ a0 = s_pose[r*10 + f0-32]; p0 = a0; }
        else if (f0 < 47){ a0 = s_ap[r*10 + f0-42]; p0 = s_ap[r*10+5 + f0-42]; }
        if (f0+1 < 42){ a1 = s_pose[r*10 + f0-31]; p1 = a1; }
        else if (f0+1 < 47){ a1 = s_ap[r*10 + f0-41]; p1 = s_ap[r*10+5 + f0-41]; }
        size_t word = (size_t)blockIdx.x*512 + (4+ft4)*64 + r*4 + wi;
        stA[word]=pk2(a0,a1);
        stP[word]=pk2(p0,p1);
    }
}

// ---------------- kAB: fused attention + SAP/AV/f1 + mix. 4 waves = 4 tiles = 8 batches/block.
// Phase A (per-wave): E=tanh(st@se+b); T=E@M+u; weight=softmax(T·E^T/sqrt128) -> s_w + wout.
// Phase B (per-wave): SAP/AV/f1 both variants -> A64/P64; then block-wide b64 + final mix.
__global__ __launch_bounds__(256,2) void kAB(const unsigned* __restrict__ ws,
        const float* __restrict__ se_b,
        const float* __restrict__ sap_b, const float* __restrict__ av_b,
        const float* __restrict__ f1_b, const float* __restrict__ f2_w,
        const float* __restrict__ f2_b,
        float* __restrict__ wout, float* __restrict__ value){
    __shared__ unsigned U1[8192];     // 32KB: phaseA [wv]{E|T}; phaseB [wv]{SAPa/AVa|SAPp/AVp}; then b64
    __shared__ unsigned sA64[2304];   // bf16 [64 rows][72]
    __shared__ unsigned sP64[2304];
    __shared__ float s_w[512];        // weight for 8 batches
    __shared__ float s_bias[384];     // sap_b | av_b | f1_b | f2_w
    __shared__ float s_ub[256];       // u | se_b
    const int t = threadIdx.x;
    const int wv = t>>6, lane = t&63;
    const int g = lane>>4, c = lane&15;
    for (int q=t; q<384; q+=256)
        s_bias[q] = (q<128)? sap_b[q] : (q<256)? av_b[q-128] : (q<320)? f1_b[q-256] : f2_w[q-320];
    if (t < 256) s_ub[t] = (t<128)? ((const float*)ws)[OFF_U+t] : se_b[t-128];
    __syncthreads();
    const int tile = blockIdx.x*4 + wv;
    const unsigned* stA = ws + OFF_STA + (size_t)tile*512;
    const unsigned* stP = ws + OFF_STP + (size_t)tile*512;
    unsigned* eB = &U1[wv*2048];         // phase A: E
    unsigned* tB = &U1[wv*2048 + 1024];  // phase A: T
    // ---- Phase A ----
    {
        f32x4 acc[8];
        #pragma unroll
        for (int i=0;i<8;++i) acc[i] = (f32x4){0.f,0.f,0.f,0.f};
        #pragma unroll
        for (int kt=0; kt<2; ++kt){
            short8 bf = fragld(stA + kt*256 + lane*4);
            #pragma unroll
            for (int ft=0; ft<8; ++ft){
                short8 af = fragld(ws + OFF_SE + ft*512 + kt*256 + lane*4);
                acc[ft] = MFMA(af, bf, acc[ft]);
            }
        }
        #pragma unroll
        for (int ft=0; ft<8; ++ft){
            const float* bp = &s_ub[128 + ft*16 + g*4];
            float d0 = fast_tanh(acc[ft][0]+bp[0]);
            float d1 = fast_tanh(acc[ft][1]+bp[1]);
            float d2 = fast_tanh(acc[ft][2]+bp[2]);
            float d3 = fast_tanh(acc[ft][3]+bp[3]);
            int word = (2*ft + (g>>1))*64 + c*4 + (g&1)*2;
            *(uint2*)&eB[word] = make_uint2(pk2(d0,d1), pk2(d2,d3));
        }
        f32x4 acc2[8];
        #pragma unroll
        for (int i=0;i<8;++i) acc2[i] = (f32x4){0.f,0.f,0.f,0.f};
        #pragma unroll
        for (int kt=0; kt<4; ++kt){
            short8 ef = fragld(&eB[kt*256 + lane*4]);
            #pragma unroll
            for (int ft=0; ft<8; ++ft){
                short8 mf = fragld(ws + OFF_M + ft*1024 + kt*256 + lane*4);
                acc2[ft] = MFMA(mf, ef, acc2[ft]);
            }
        }
        #pragma unroll
        for (int ft=0; ft<8; ++ft){
            const float* up = &s_ub[ft*16 + g*4];
            int word = (2*ft + (g>>1))*64 + c*4 + (g&1)*2;
            *(uint2*)&tB[word] = make_uint2(pk2(acc2[ft][0]+up[0], acc2[ft][1]+up[1]),
                                            pk2(acc2[ft][2]+up[2], acc2[ft][3]+up[3]));
        }
        f32x4 L = (f32x4){0.f,0.f,0.f,0.f};
        #pragma unroll
        for (int kt=0; kt<4; ++kt){
            short8 tf = fragld(&tB[kt*256 + lane*4]);
            short8 ef = fragld(&eB[kt*256 + lane*4]);
            L = MFMA(tf, ef, L);
        }
        float sc[4];
        #pragma unroll
        for (int q=0;q<4;++q) sc[q] = L[q]*0.08838834764831845f;
        #pragma unroll
        for (int q=0;q<4;++q){
            float m = sc[q];
            m = fmaxf(m, __shfl_xor(m,1));
            m = fmaxf(m, __shfl_xor(m,2));
            m = fmaxf(m, __shfl_xor(m,4));
            float ex = __expf(sc[q]-m);
            float su = ex;
            su += __shfl_xor(su,1);
            su += __shfl_xor(su,2);
            su += __shfl_xor(su,4);
            sc[q] = ex/su;
        }
        if ((c>>3) == (g>>1)){
            int lb = wv*2 + (g>>1);                  // local batch 0..7
            int batch = tile*2 + (g>>1);
            int idx = ((g&1)*4)*8 + (c&7);
            #pragma unroll
            for (int q=0;q<4;++q){
                float v = sc[q];
                wout[batch*64 + idx + q*8] = v;
                s_w[lb*64 + idx + q*8] = v;
            }
        }
    }
    // ---- Phase B ---- (overwrite eB/tB with SAPa/SAPp then AVa/AVp; wave-private)
    unsigned* bufA = eB;
    unsigned* bufP = tB;
    {
        f32x4 acc[2][8];
        #pragma unroll
        for (int v=0;v<2;++v)
          #pragma unroll
          for (int i=0;i<8;++i) acc[v][i] = (f32x4){0.f,0.f,0.f,0.f};
        #pragma unroll
        for (int kt=0; kt<2; ++kt){
            short8 bfA = fragld(stA + kt*256 + lane*4);
            short8 bfP = fragld(stP + kt*256 + lane*4);
            #pragma unroll
            for (int ft=0; ft<8; ++ft){
                short8 af = fragld(ws + OFF_SAP + ft*512 + kt*256 + lane*4);
                acc[0][ft] = MFMA(af, bfA, acc[0][ft]);
                acc[1][ft] = MFMA(af, bfP, acc[1][ft]);
            }
        }
        #pragma unroll
        for (int v=0;v<2;++v){
            unsigned* dst = v? bufP : bufA;
            #pragma unroll
            for (int ft=0; ft<8; ++ft){
                const float* bp = &s_bias[ft*16 + g*4];
                float d0 = fast_tanh(acc[v][ft][0]+bp[0]);
                float d1 = fast_tanh(acc[v][ft][1]+bp[1]);
                float d2 = fast_tanh(acc[v][ft][2]+bp[2]);
                float d3 = fast_tanh(acc[v][ft][3]+bp[3]);
                int word = (2*ft + (g>>1))*64 + c*4 + (g&1)*2;
                *(uint2*)&dst[word] = make_uint2(pk2(d0,d1), pk2(d2,d3));
            }
        }
        f32x4 acc2[2][8];
        #pragma unroll
        for (int v=0;v<2;++v)
          #pragma unroll
          for (int i=0;i<8;++i) acc2[v][i] = (f32x4){0.f,0.f,0.f,0.f};
        #pragma unroll
        for (int kt=0; kt<4; ++kt){
            short8 bfA = fragld(&bufA[kt*256 + lane*4]);
            short8 bfP = fragld(&bufP[kt*256 + lane*4]);
            #pragma unroll
            for (int ft=0; ft<8; ++ft){
                short8 af = fragld(ws + OFF_AV + ft*1024 + kt*256 + lane*4);
                acc2[0][ft] = MFMA(af, bfA, acc2[0][ft]);
                acc2[1][ft] = MFMA(af, bfP, acc2[1][ft]);
            }
        }
        #pragma unroll
        for (int v=0;v<2;++v){
            unsigned* dst = v? bufP : bufA;
            #pragma unroll
            for (int ft=0; ft<8; ++ft){
                const float* bp = &s_bias[128 + ft*16 + g*4];
                float d0 = fast_tanh(acc2[v][ft][0]+bp[0]);
                float d1 = fast_tanh(acc2[v][ft][1]+bp[1]);
                float d2 = fast_tanh(acc2[v][ft][2]+bp[2]);
                float d3 = fast_tanh(acc2[v][ft][3]+bp[3]);
                int word = (2*ft + (g>>1))*64 + c*4 + (g&1)*2;
                *(uint2*)&dst[word] = make_uint2(pk2(d0,d1), pk2(d2,d3));
            }
        }
        f32x4 acc3[2][4];
        #pragma unroll
        for (int v=0;v<2;++v)
          #pragma unroll
          for (int i=0;i<4;++i) acc3[v][i] = (f32x4){0.f,0.f,0.f,0.f};
        #pragma unroll
        for (int kt=0; kt<4; ++kt){
            short8 bfA = fragld(&bufA[kt*256 + lane*4]);
            short8 bfP = fragld(&bufP[kt*256 + lane*4]);
            #pragma unroll
            for (int ft=0; ft<4; ++ft){
                short8 af = fragld(ws + OFF_F1 + ft*1024 + kt*256 + lane*4);
                acc3[0][ft] = MFMA(af, bfA, acc3[0][ft]);
                acc3[1][ft] = MFMA(af, bfP, acc3[1][ft]);
            }
        }
        int row = wv*16 + c;
        #pragma unroll
        for (int v=0;v<2;++v){
            unsigned* dst = v? sP64 : sA64;
            #pragma unroll
            for (int ft=0; ft<4; ++ft){
                int idx = row*36 + ft*8 + 2*g;
                *(uint2*)&dst[idx] = make_uint2(pk2(acc3[v][ft][0], acc3[v][ft][1]),
                                                pk2(acc3[v][ft][2], acc3[v][ft][3]));
            }
        }
    }
    __syncthreads();   // A64/P64 + s_w complete; U1 (buf) now dead -> reuse as b64
    float* s_b64 = (float*)U1;  // [64 rows][68]
    const unsigned short* A16 = (const unsigned short*)sA64;
    const unsigned short* P16 = (const unsigned short*)sP64;
    #pragma unroll
    for (int k=0; k<16; ++k){
        int e = t + 256*k;
        int bq = e>>9, a = (e>>6)&7, cc = e&63;
        const float* wp = &s_w[bq*64 + a*8];
        float acc4 = 0.f;
        #pragma unroll
        for (int j=0;j<8;++j) acc4 += wp[j]*bf2f(A16[(bq*8+j)*72 + cc]);
        s_b64[(bq*8+a)*68 + cc] = acc4;
    }
    __syncthreads();
    #pragma unroll
    for (int k=0; k<2; ++k){
        int o = t + 256*k;
        int bq = o>>6, a = (o>>3)&7, i = o&7;
        float w_ai = s_w[bq*64 + a*8 + i];
        const float* pb = &s_b64[(bq*8+a)*68];
        const unsigned short* pA = &A16[(bq*8+i)*72];
        const unsigned short* pP = &P16[(bq*8+i)*72];
        float acc5 = 0.f;
        #pragma unroll 8
        for (int cc=0; cc<64; ++cc){
            float dd = bf2f(pP[cc]) - bf2f(pA[cc]);
            acc5 += fast_tanh(pb[cc] + w_ai*dd + s_bias[256+cc]) * s_bias[320+cc];
        }
        value[(size_t)blockIdx.x*512 + o] = acc5 + f2_b[0];
    }
}

extern "C" void kernel_launch(void* const* d_in, const int* in_sizes, int n_in,
                              void* d_out, int out_size, void* d_ws, size_t ws_size,
                              hipStream_t stream){
    const float* agent_states = (const float*)d_in[0];
    const float* pos    = (const float*)d_in[1];
    const float* oneh   = (const float*)d_in[2];
    const float* pols   = (const float*)d_in[3];
    const float* acts   = (const float*)d_in[4];
    const float* w1     = (const float*)d_in[5];
    const float* b1     = (const float*)d_in[6];
    const float* w2     = (const float*)d_in[7];
    const float* b2     = (const float*)d_in[8];
    const float* se_w   = (const float*)d_in[9];
    const float* se_b   = (const float*)d_in[10];
    const float* key_w  = (const float*)d_in[11];
    const float* query_w= (const float*)d_in[13];
    const float* query_b= (const float*)d_in[14];
    const float* sap_w  = (const float*)d_in[15];
    const float* sap_b  = (const float*)d_in[16];
    const float* av_w   = (const float*)d_in[17];
    const float* av_b   = (const float*)d_in[18];
    const float* f1_w   = (const float*)d_in[19];
    const float* f1_b   = (const float*)d_in[20];
    const float* f2_w   = (const float*)d_in[21];
    const float* f2_b   = (const float*)d_in[22];

    unsigned* ws = (unsigned*)d_ws;
    unsigned* stA = ws + OFF_STA;
    unsigned* stP = ws + OFF_STP;

    float* value = (float*)d_out;
    float* wout  = value + (size_t)NB*NA*NA;

    kW<<<131, 256, 0, stream>>>(se_w, sap_w, av_w, f1_w, query_w, key_w, query_b, w2, ws);
    k1_conv<<<BN/16, 256, 0, stream>>>(agent_states, pos, oneh, acts, pols,
                                       w1, b1, b2, ((const float*)ws)+OFF_W2T, stA, stP);
    kAB<<<BN/64, 256, 0, stream>>>(ws, se_b, sap_b, av_b, f1_b, f2_w, f2_b, wout, value);
}

// Round 7
// 66.098 us; speedup vs baseline: 3.1967x; 1.0285x over previous
//
#include <hip/hip_runtime.h>
#include <math.h>

#define NB 4096
#define NA 8
#define BN (NB*NA)   // 32768

// ws layout (u32 words)
#define OFF_SE   0            // se pack:  8 tiles * 512
#define OFF_SAP  4096         // sap pack: 8 tiles * 512
#define OFF_AV   8192         // av pack:  8 tiles * 1024
#define OFF_F1   16384        // f1 pack:  4 tiles * 1024
#define OFF_M    20480        // M pack:   8 tiles * 1024
#define OFF_U    28672        // u: 128 floats
#define OFF_W2T  28800        // conv2 w transposed [144][32] f32
#define OFF_STA  33408        // statesA pack: 2048 tiles * 512
#define OFF_STP  (33408+1048576)

typedef short short8 __attribute__((ext_vector_type(8)));
typedef float f32x4 __attribute__((ext_vector_type(4)));

#define MFMA(a,b,c) __builtin_amdgcn_mfma_f32_16x16x32_bf16(a,b,c,0,0,0)

__device__ __forceinline__ float fast_tanh(float x){
    float e = __expf(2.0f*x);
    return 1.0f - 2.0f*__builtin_amdgcn_rcpf(e+1.0f);
}
__device__ __forceinline__ unsigned bfr(float x){
    unsigned u = __float_as_uint(x);
    return (u + 0x7fffu + ((u>>16)&1u)) >> 16;
}
__device__ __forceinline__ unsigned pk2(float lo, float hi){
    return bfr(lo) | (bfr(hi)<<16);
}
__device__ __forceinline__ float bf2f(unsigned short s){
    return __uint_as_float(((unsigned)s)<<16);
}
__device__ __forceinline__ short8 fragld(const unsigned* p){
    union { uint4 u; short8 s; } cv;
    cv.u = *(const uint4*)p;
    return cv.s;
}

// ---------------- kW: pack all weights as A-fragments (pack16 of W^T), compute M, u, w2t ----
__global__ __launch_bounds__(256) void kW(const float* __restrict__ se_w,
        const float* __restrict__ sap_w, const float* __restrict__ av_w,
        const float* __restrict__ f1_w, const float* __restrict__ qw,
        const float* __restrict__ kw, const float* __restrict__ qb,
        const float* __restrict__ w2,
        unsigned* __restrict__ ws){
    int idx = blockIdx.x*256 + threadIdx.x;
    if (idx < 4096){                       // sePk (F=64 pad, rows f2=128)
        int w = idx, tile = w>>9, rem = w&511;
        int ft = rem>>6, r2 = (rem>>2)&15, wi = rem&3;
        int f2 = tile*16 + r2, f1 = ft*8 + wi*2;
        float lo = (f1   < 42)? se_w[f1*128+f2]     : 0.f;
        float hi = (f1+1 < 42)? se_w[(f1+1)*128+f2] : 0.f;
        ws[OFF_SE + w] = pk2(lo,hi);
    } else if (idx < 8192){                // sapPk (F=64 pad, limit 47)
        int w = idx-4096, tile = w>>9, rem = w&511;
        int ft = rem>>6, r2 = (rem>>2)&15, wi = rem&3;
        int f2 = tile*16 + r2, f1 = ft*8 + wi*2;
        float lo = (f1   < 47)? sap_w[f1*128+f2]     : 0.f;
        float hi = (f1+1 < 47)? sap_w[(f1+1)*128+f2] : 0.f;
        ws[OFF_SAP + w] = pk2(lo,hi);
    } else if (idx < 16384){               // avPk (F=128)
        int w = idx-8192, tile = w>>10, rem = w&1023;
        int ft = rem>>6, r2 = (rem>>2)&15, wi = rem&3;
        int f2 = tile*16 + r2, f1 = ft*8 + wi*2;
        ws[OFF_AV + w] = pk2(av_w[f1*128+f2], av_w[(f1+1)*128+f2]);
    } else if (idx < 20480){               // f1Pk (F=128, rows f2=64)
        int w = idx-16384, tile = w>>10, rem = w&1023;
        int ft = rem>>6, r2 = (rem>>2)&15, wi = rem&3;
        int f2 = tile*16 + r2, f1 = ft*8 + wi*2;
        ws[OFF_F1 + w] = pk2(f1_w[f1*64+f2], f1_w[(f1+1)*64+f2]);
    } else if (idx < 28672){               // MPk: M[e][f2] = qw[e]·kw[f2]
        int w = idx-20480, tile = w>>10, rem = w&1023;
        int ft = rem>>6, r2 = (rem>>2)&15, wi = rem&3;
        int f2 = tile*16 + r2, e0 = ft*8 + wi*2;
        float lo=0.f, hi=0.f;
        for (int d=0; d<128; ++d){
            float kv = kw[f2*128+d];
            lo += qw[e0*128+d]*kv;
            hi += qw[(e0+1)*128+d]*kv;
        }
        ws[OFF_M + w] = pk2(lo,hi);
    } else if (idx < 28800){               // u[f] = qb·kw[f]
        int f = idx-28672;
        float a = 0.f;
        for (int d=0; d<128; ++d) a += qb[d]*kw[f*128+d];
        ((float*)ws)[OFF_U + f] = a;
    } else if (idx < 33408){               // w2t[k][oc] = w2[oc][k]
        int w = idx-28800;
        int k = w>>5, oc = w&31;
        ((float*)ws)[OFF_W2T + w] = w2[oc*144 + k];
    }
}

// ---------------- k1: conv encoder -> statesA/statesP packs (16 agents = 1 tile per block) ---
__global__ __launch_bounds__(256) void k1_conv(const float* __restrict__ xin,
        const float* __restrict__ pos, const float* __restrict__ oneh,
        const float* __restrict__ acts, const float* __restrict__ pols,
        const float* __restrict__ w1, const float* __restrict__ b1,
        const float* __restrict__ b2,
        const float* __restrict__ wsW2T,
        unsigned* __restrict__ stA, unsigned* __restrict__ stP){
    __shared__ float s_in[16*76];     // 4864 B
    __shared__ float s_w1[432];
    __shared__ float s_b1[16];
    __shared__ float s_w2t[4608];     // 18432 B, [k][32]
    __shared__ float s_b2[32];
    __shared__ float s_h1[144*17];    // 9792 B, [k][agent] pad 17
    __shared__ float s_ap[160];       // [agent][act5|pol5]
    __shared__ float s_pose[160];     // [agent][pos2|oneh8]
    const int t = threadIdx.x;
    const int g0 = blockIdx.x*16;
    for (int q=t; q<1152; q+=256)
        *(float4*)&s_w2t[q*4] = *(const float4*)&wsW2T[q*4];
    for (int q=t; q<432; q+=256) s_w1[q] = w1[q];
    if (t<16) s_b1[t]=b1[t];
    if (t<32) s_b2[t]=b2[t];
    for (int q=t; q<1200; q+=256){
        int ag=q/75, r=q-ag*75;
        s_in[ag*76+r]=xin[(size_t)g0*75+q];
    }
    for (int q=t; q<160; q+=256){
        int ag=q/10, k=q-ag*10;
        s_ap[q]   = (k<5)? acts[(size_t)(g0+ag)*5+k] : pols[(size_t)(g0+ag)*5+(k-5)];
        s_pose[q] = (k<2)? pos[(size_t)(g0+ag)*2+k]  : oneh[(size_t)(g0+ag)*8+(k-2)];
    }
    __syncthreads();
    {
        const int ag = t&15, oc = t>>4;
        float w[27];
        #pragma unroll
        for (int i=0;i<27;++i) w[i]=s_w1[oc*27+i];
        float out[9];
        float bb = s_b1[oc];
        #pragma unroll
        for (int p=0;p<9;++p) out[p]=bb;
        #pragma unroll
        for (int ic=0;ic<3;++ic){
            float pin[25];
            #pragma unroll
            for (int i=0;i<25;++i) pin[i]=s_in[ag*76+ic*25+i];
            #pragma unroll
            for (int y=0;y<3;++y)
              #pragma unroll
              for (int x=0;x<3;++x)
                #pragma unroll
                for (int ky=0;ky<3;++ky)
                  #pragma unroll
                  for (int kx=0;kx<3;++kx)
                    out[y*3+x] += pin[(y+ky)*5+(x+kx)] * w[ic*9+ky*3+kx];
        }
        #pragma unroll
        for (int p=0;p<9;++p){
            float v = out[p];
            v = (v>=0.f)? v : 0.01f*v;
            s_h1[(oc*9+p)*17 + ag] = v;
        }
    }
    __syncthreads();
    {
        const int ag = t>>4, o2 = t&15, oc = o2*2;
        float a0 = s_b2[oc], a1 = s_b2[oc+1];
        #pragma unroll 8
        for (int k=0;k<144;++k){
            float h = s_h1[k*17+ag];
            float2 wv = *(const float2*)&s_w2t[k*32+oc];
            a0 += h*wv.x; a1 += h*wv.y;
        }
        a0 = (a0>=0.f)? a0 : 0.01f*a0;
        a1 = (a1>=0.f)? a1 : 0.01f*a1;
        unsigned pw = pk2(a0,a1);
        size_t word = (size_t)blockIdx.x*512 + (o2>>2)*64 + ag*4 + (o2&3);
        stA[word]=pw; stP[word]=pw;
    }
    {
        const int ft4 = t>>6, r = (t>>2)&15, wi = t&3;
        const int f0 = 32 + ft4*8 + wi*2;
        float a0=0.f,a1=0.f,p0=0.f,p1=0.f;
        if (f0 < 42){ a0 = s_pose[r*10 + f0-32]; p0 = a0; }
        else if (f0 < 47){ a0 = s_ap[r*10 + f0-42]; p0 = s_ap[r*10+5 + f0-42]; }
        if (f0+1 < 42){ a1 = s_pose[r*10 + f0-31]; p1 = a1; }
        else if (f0+1 < 47){ a1 = s_ap[r*10 + f0-41]; p1 = s_ap[r*10+5 + f0-41]; }
        size_t word = (size_t)blockIdx.x*512 + (4+ft4)*64 + r*4 + wi;
        stA[word]=pk2(a0,a1);
        stP[word]=pk2(p0,p1);
    }
}

// ---------------- kAB: fused, with double-buffered cooperative LDS weight staging ----------
// 4 waves = 4 tiles = 8 batches/block, grid 512. 14 weight chunks of 2048 words.
__global__ __launch_bounds__(256,2) void kAB(const unsigned* __restrict__ ws,
        const float* __restrict__ se_b,
        const float* __restrict__ sap_b, const float* __restrict__ av_b,
        const float* __restrict__ f1_b, const float* __restrict__ f2_w,
        const float* __restrict__ f2_b,
        float* __restrict__ wout, float* __restrict__ value){
    __shared__ unsigned s_stage[2][2048];  // 16 KB
    __shared__ unsigned U1[5120];          // 20 KB: per-wave {1024 scratch + 256 T}; tail b64
    __shared__ unsigned sA64[2176];        // bf16 [64 rows][68]
    __shared__ unsigned sP64[2176];
    __shared__ float s_w[512];
    __shared__ float s_bias[384];          // sap_b | av_b | f1_b | f2_w
    __shared__ float s_ub[256];            // u | se_b
    const int t = threadIdx.x;
    const int wv = t>>6, lane = t&63;
    const int g = lane>>4, c = lane&15;
    const int tile = blockIdx.x*4 + wv;
    const unsigned* stA = ws + OFF_STA + (size_t)tile*512;
    const unsigned* stP = ws + OFF_STP + (size_t)tile*512;
    // persistent state fragments (reused by SE and SAP phases)
    short8 bfA0 = fragld(stA + lane*4);
    short8 bfA1 = fragld(stA + 256 + lane*4);
    short8 bfP0 = fragld(stP + lane*4);
    short8 bfP1 = fragld(stP + 256 + lane*4);
    for (int q=t; q<384; q+=256)
        s_bias[q] = (q<128)? sap_b[q] : (q<256)? av_b[q-128] : (q<320)? f1_b[q-256] : f2_w[q-320];
    s_ub[t] = (t<128)? ((const float*)ws)[OFF_U+t] : se_b[t-128];
    unsigned* wS = &U1[wv*1280];          // 1024-word per-wave repack scratch
    unsigned* tS = &U1[wv*1280 + 1024];   // 256-word T scratch

    uint4 r0, r1;
#define PREF(off) { r0 = *(const uint4*)(ws + (off) + t*4); \
                    r1 = *(const uint4*)(ws + (off) + 1024 + t*4); }
#define WR(b) { *(uint4*)&s_stage[b][t*4] = r0; *(uint4*)&s_stage[b][1024 + t*4] = r1; }

    PREF(OFF_SE); WR(0);
    __syncthreads();

    // ---- SE chunks c0,c1 -> acc[8] ----
    f32x4 acc[8];
    #pragma unroll
    for (int i=0;i<8;++i) acc[i] = (f32x4){0.f,0.f,0.f,0.f};
    PREF(OFF_SE + 2048);
    #pragma unroll
    for (int ft=0; ft<4; ++ft){
        short8 a0 = fragld(&s_stage[0][ft*512 + lane*4]);
        short8 a1 = fragld(&s_stage[0][ft*512 + 256 + lane*4]);
        acc[ft] = MFMA(a0, bfA0, acc[ft]);
        acc[ft] = MFMA(a1, bfA1, acc[ft]);
    }
    WR(1); __syncthreads();
    PREF(OFF_M);
    #pragma unroll
    for (int ft=4; ft<8; ++ft){
        short8 a0 = fragld(&s_stage[1][(ft-4)*512 + lane*4]);
        short8 a1 = fragld(&s_stage[1][(ft-4)*512 + 256 + lane*4]);
        acc[ft] = MFMA(a0, bfA0, acc[ft]);
        acc[ft] = MFMA(a1, bfA1, acc[ft]);
    }
    WR(0);
    // E build -> wS, cache ef[4]
    #pragma unroll
    for (int ft=0; ft<8; ++ft){
        const float* bp = &s_ub[128 + ft*16 + g*4];
        float d0 = fast_tanh(acc[ft][0]+bp[0]);
        float d1 = fast_tanh(acc[ft][1]+bp[1]);
        float d2 = fast_tanh(acc[ft][2]+bp[2]);
        float d3 = fast_tanh(acc[ft][3]+bp[3]);
        int word = (2*ft + (g>>1))*64 + c*4 + (g&1)*2;
        *(uint2*)&wS[word] = make_uint2(pk2(d0,d1), pk2(d2,d3));
    }
    short8 ef[4];
    #pragma unroll
    for (int kt=0; kt<4; ++kt) ef[kt] = fragld(&wS[kt*256 + lane*4]);
    __syncthreads();

    // ---- M chunks c2..c5, fused T-write + logits ----
    f32x4 L = (f32x4){0.f,0.f,0.f,0.f};
    #pragma unroll
    for (int i=0; i<4; ++i){
        const int nextOff = (i<3)? (OFF_M + (i+1)*2048) : OFF_SAP;
        PREF(nextOff);
        f32x4 a2[2];
        a2[0] = (f32x4){0.f,0.f,0.f,0.f};
        a2[1] = (f32x4){0.f,0.f,0.f,0.f};
        #pragma unroll
        for (int ftl=0; ftl<2; ++ftl)
          #pragma unroll
          for (int kt=0; kt<4; ++kt){
            short8 mf = fragld(&s_stage[i&1][ftl*1024 + kt*256 + lane*4]);
            a2[ftl] = MFMA(mf, ef[kt], a2[ftl]);
          }
        WR((i+1)&1);
        #pragma unroll
        for (int ftl=0; ftl<2; ++ftl){
            const float* up = &s_ub[(2*i+ftl)*16 + g*4];
            int word = (2*ftl + (g>>1))*64 + c*4 + (g&1)*2;
            *(uint2*)&tS[word] = make_uint2(pk2(a2[ftl][0]+up[0], a2[ftl][1]+up[1]),
                                            pk2(a2[ftl][2]+up[2], a2[ftl][3]+up[3]));
        }
        short8 tf = fragld(&tS[lane*4]);
        L = MFMA(tf, ef[i], L);
        __syncthreads();
    }
    // softmax -> s_w + wout
    {
        float sc[4];
        #pragma unroll
        for (int q=0;q<4;++q) sc[q] = L[q]*0.08838834764831845f;
        #pragma unroll
        for (int q=0;q<4;++q){
            float m = sc[q];
            m = fmaxf(m, __shfl_xor(m,1));
            m = fmaxf(m, __shfl_xor(m,2));
            m = fmaxf(m, __shfl_xor(m,4));
            float ex = __expf(sc[q]-m);
            float su = ex;
            su += __shfl_xor(su,1);
            su += __shfl_xor(su,2);
            su += __shfl_xor(su,4);
            sc[q] = ex/su;
        }
        if ((c>>3) == (g>>1)){
            int lb = wv*2 + (g>>1);
            int batch = tile*2 + (g>>1);
            int idx = ((g&1)*4)*8 + (c&7);
            #pragma unroll
            for (int q=0;q<4;++q){
                float v = sc[q];
                wout[batch*64 + idx + q*8] = v;
                s_w[lb*64 + idx + q*8] = v;
            }
        }
    }

    // ---- SAP chunks c6,c7 -> aS[2][8] ----
    f32x4 aS[2][8];
    #pragma unroll
    for (int v=0;v<2;++v)
      #pragma unroll
      for (int i=0;i<8;++i) aS[v][i] = (f32x4){0.f,0.f,0.f,0.f};
    PREF(OFF_SAP + 2048);
    #pragma unroll
    for (int ft=0; ft<4; ++ft){
        short8 a0 = fragld(&s_stage[0][ft*512 + lane*4]);
        short8 a1 = fragld(&s_stage[0][ft*512 + 256 + lane*4]);
        aS[0][ft] = MFMA(a0, bfA0, aS[0][ft]);
        aS[0][ft] = MFMA(a1, bfA1, aS[0][ft]);
        aS[1][ft] = MFMA(a0, bfP0, aS[1][ft]);
        aS[1][ft] = MFMA(a1, bfP1, aS[1][ft]);
    }
    WR(1); __syncthreads();
    PREF(OFF_AV);
    #pragma unroll
    for (int ft=4; ft<8; ++ft){
        short8 a0 = fragld(&s_stage[1][(ft-4)*512 + lane*4]);
        short8 a1 = fragld(&s_stage[1][(ft-4)*512 + 256 + lane*4]);
        aS[0][ft] = MFMA(a0, bfA0, aS[0][ft]);
        aS[0][ft] = MFMA(a1, bfA1, aS[0][ft]);
        aS[1][ft] = MFMA(a0, bfP0, aS[1][ft]);
        aS[1][ft] = MFMA(a1, bfP1, aS[1][ft]);
    }
    WR(0);
    // SAP build (variant A then P through the single scratch), cache frags
    short8 spA[4], spP[4];
    #pragma unroll
    for (int ft=0; ft<8; ++ft){
        const float* bp = &s_bias[ft*16 + g*4];
        float d0 = fast_tanh(aS[0][ft][0]+bp[0]);
        float d1 = fast_tanh(aS[0][ft][1]+bp[1]);
        float d2 = fast_tanh(aS[0][ft][2]+bp[2]);
        float d3 = fast_tanh(aS[0][ft][3]+bp[3]);
        int word = (2*ft + (g>>1))*64 + c*4 + (g&1)*2;
        *(uint2*)&wS[word] = make_uint2(pk2(d0,d1), pk2(d2,d3));
    }
    #pragma unroll
    for (int kt=0; kt<4; ++kt) spA[kt] = fragld(&wS[kt*256 + lane*4]);
    #pragma unroll
    for (int ft=0; ft<8; ++ft){
        const float* bp = &s_bias[ft*16 + g*4];
        float d0 = fast_tanh(aS[1][ft][0]+bp[0]);
        float d1 = fast_tanh(aS[1][ft][1]+bp[1]);
        float d2 = fast_tanh(aS[1][ft][2]+bp[2]);
        float d3 = fast_tanh(aS[1][ft][3]+bp[3]);
        int word = (2*ft + (g>>1))*64 + c*4 + (g&1)*2;
        *(uint2*)&wS[word] = make_uint2(pk2(d0,d1), pk2(d2,d3));
    }
    #pragma unroll
    for (int kt=0; kt<4; ++kt) spP[kt] = fragld(&wS[kt*256 + lane*4]);
    __syncthreads();

    // ---- AV chunks c8..c11 -> aV[2][8] ----
    f32x4 aV[2][8];
    #pragma unroll
    for (int v=0;v<2;++v)
      #pragma unroll
      for (int i=0;i<8;++i) aV[v][i] = (f32x4){0.f,0.f,0.f,0.f};
    short8 avA[4], avP[4];
    #pragma unroll
    for (int i=0; i<4; ++i){
        const int nextOff = (i<3)? (OFF_AV + (i+1)*2048) : OFF_F1;
        PREF(nextOff);
        #pragma unroll
        for (int ftl=0; ftl<2; ++ftl){
            const int ft = 2*i + ftl;
            #pragma unroll
            for (int kt=0; kt<4; ++kt){
                short8 af = fragld(&s_stage[i&1][ftl*1024 + kt*256 + lane*4]);
                aV[0][ft] = MFMA(af, spA[kt], aV[0][ft]);
                aV[1][ft] = MFMA(af, spP[kt], aV[1][ft]);
            }
        }
        WR((i+1)&1);
        if (i==3){
            // AV build (A then P through scratch), cache frags
            #pragma unroll
            for (int ft=0; ft<8; ++ft){
                const float* bp = &s_bias[128 + ft*16 + g*4];
                float d0 = fast_tanh(aV[0][ft][0]+bp[0]);
                float d1 = fast_tanh(aV[0][ft][1]+bp[1]);
                float d2 = fast_tanh(aV[0][ft][2]+bp[2]);
                float d3 = fast_tanh(aV[0][ft][3]+bp[3]);
                int word = (2*ft + (g>>1))*64 + c*4 + (g&1)*2;
                *(uint2*)&wS[word] = make_uint2(pk2(d0,d1), pk2(d2,d3));
            }
            #pragma unroll
            for (int kt=0; kt<4; ++kt) avA[kt] = fragld(&wS[kt*256 + lane*4]);
            #pragma unroll
            for (int ft=0; ft<8; ++ft){
                const float* bp = &s_bias[128 + ft*16 + g*4];
                float d0 = fast_tanh(aV[1][ft][0]+bp[0]);
                float d1 = fast_tanh(aV[1][ft][1]+bp[1]);
                float d2 = fast_tanh(aV[1][ft][2]+bp[2]);
                float d3 = fast_tanh(aV[1][ft][3]+bp[3]);
                int word = (2*ft + (g>>1))*64 + c*4 + (g&1)*2;
                *(uint2*)&wS[word] = make_uint2(pk2(d0,d1), pk2(d2,d3));
            }
            #pragma unroll
            for (int kt=0; kt<4; ++kt) avP[kt] = fragld(&wS[kt*256 + lane*4]);
        }
        __syncthreads();
    }

    // ---- F1 chunks c12,c13 -> aF[2][4] ----
    f32x4 aF[2][4];
    #pragma unroll
    for (int v=0;v<2;++v)
      #pragma unroll
      for (int i=0;i<4;++i) aF[v][i] = (f32x4){0.f,0.f,0.f,0.f};
    PREF(OFF_F1 + 2048);
    #pragma unroll
    for (int ftl=0; ftl<2; ++ftl)
      #pragma unroll
      for (int kt=0; kt<4; ++kt){
        short8 af = fragld(&s_stage[0][ftl*1024 + kt*256 + lane*4]);
        aF[0][ftl] = MFMA(af, avA[kt], aF[0][ftl]);
        aF[1][ftl] = MFMA(af, avP[kt], aF[1][ftl]);
      }
    WR(1); __syncthreads();
    #pragma unroll
    for (int ftl=0; ftl<2; ++ftl)
      #pragma unroll
      for (int kt=0; kt<4; ++kt){
        short8 af = fragld(&s_stage[1][ftl*1024 + kt*256 + lane*4]);
        aF[0][2+ftl] = MFMA(af, avA[kt], aF[0][2+ftl]);
        aF[1][2+ftl] = MFMA(af, avP[kt], aF[1][2+ftl]);
      }
    {
        int row = wv*16 + c;
        #pragma unroll
        for (int v=0;v<2;++v){
            unsigned* dst = v? sP64 : sA64;
            #pragma unroll
            for (int ft=0; ft<4; ++ft){
                int idx = row*34 + ft*8 + 2*g;
                *(uint2*)&dst[idx] = make_uint2(pk2(aF[v][ft][0], aF[v][ft][1]),
                                                pk2(aF[v][ft][2], aF[v][ft][3]));
            }
        }
    }
    __syncthreads();
    // ---- tail: b64 + final mix ----
    float* s_b64 = (float*)U1;  // [64 rows][68]
    const unsigned short* A16 = (const unsigned short*)sA64;
    const unsigned short* P16 = (const unsigned short*)sP64;
    #pragma unroll
    for (int k=0; k<16; ++k){
        int e = t + 256*k;
        int bq = e>>9, a = (e>>6)&7, cc = e&63;
        const float* wp = &s_w[bq*64 + a*8];
        float acc4 = 0.f;
        #pragma unroll
        for (int j=0;j<8;++j) acc4 += wp[j]*bf2f(A16[(bq*8+j)*68 + cc]);
        s_b64[(bq*8+a)*68 + cc] = acc4;
    }
    __syncthreads();
    #pragma unroll
    for (int k=0; k<2; ++k){
        int o = t + 256*k;
        int bq = o>>6, a = (o>>3)&7, i = o&7;
        float w_ai = s_w[bq*64 + a*8 + i];
        const float* pb = &s_b64[(bq*8+a)*68];
        const unsigned short* pA = &A16[(bq*8+i)*68];
        const unsigned short* pP = &P16[(bq*8+i)*68];
        float acc5 = 0.f;
        #pragma unroll 8
        for (int cc=0; cc<64; ++cc){
            float dd = bf2f(pP[cc]) - bf2f(pA[cc]);
            acc5 += fast_tanh(pb[cc] + w_ai*dd + s_bias[256+cc]) * s_bias[320+cc];
        }
        value[(size_t)blockIdx.x*512 + o] = acc5 + f2_b[0];
    }
#undef PREF
#undef WR
}

extern "C" void kernel_launch(void* const* d_in, const int* in_sizes, int n_in,
                              void* d_out, int out_size, void* d_ws, size_t ws_size,
                              hipStream_t stream){
    const float* agent_states = (const float*)d_in[0];
    const float* pos    = (const float*)d_in[1];
    const float* oneh   = (const float*)d_in[2];
    const float* pols   = (const float*)d_in[3];
    const float* acts   = (const float*)d_in[4];
    const float* w1     = (const float*)d_in[5];
    const float* b1     = (const float*)d_in[6];
    const float* w2     = (const float*)d_in[7];
    const float* b2     = (const float*)d_in[8];
    const float* se_w   = (const float*)d_in[9];
    const float* se_b   = (const float*)d_in[10];
    const float* key_w  = (const float*)d_in[11];
    const float* query_w= (const float*)d_in[13];
    const float* query_b= (const float*)d_in[14];
    const float* sap_w  = (const float*)d_in[15];
    const float* sap_b  = (const float*)d_in[16];
    const float* av_w   = (const float*)d_in[17];
    const float* av_b   = (const float*)d_in[18];
    const float* f1_w   = (const float*)d_in[19];
    const float* f1_b   = (const float*)d_in[20];
    const float* f2_w   = (const float*)d_in[21];
    const float* f2_b   = (const float*)d_in[22];

    unsigned* ws = (unsigned*)d_ws;
    unsigned* stA = ws + OFF_STA;
    unsigned* stP = ws + OFF_STP;

    float* value = (float*)d_out;
    float* wout  = value + (size_t)NB*NA*NA;

    kW<<<131, 256, 0, stream>>>(se_w, sap_w, av_w, f1_w, query_w, key_w, query_b, w2, ws);
    k1_conv<<<BN/16, 256, 0, stream>>>(agent_states, pos, oneh, acts, pols,
                                       w1, b1, b2, ((const float*)ws)+OFF_W2T, stA, stP);
    kAB<<<BN/64, 256, 0, stream>>>(ws, se_b, sap_b, av_b, f1_b, f2_w, f2_b, wout, value);
}

// Round 8
// 65.361 us; speedup vs baseline: 3.2327x; 1.0113x over previous
//
#include <hip/hip_runtime.h>
#include <math.h>

#define NB 4096
#define NA 8
#define BN (NB*NA)   // 32768

// ws layout (u32 words)
#define OFF_SE   0            // se pack:  8 tiles * 512
#define OFF_SAP  4096         // sap pack: 8 tiles * 512
#define OFF_AV   8192         // av pack:  8 tiles * 1024
#define OFF_F1   16384        // f1 pack:  4 tiles * 1024
#define OFF_M    20480        // M pack:   8 tiles * 1024
#define OFF_U    28672        // u: 128 floats
#define OFF_W2T  28800        // conv2 w transposed [144][32] f32
// ws end: 33408 words

typedef short short8 __attribute__((ext_vector_type(8)));
typedef float f32x4 __attribute__((ext_vector_type(4)));

#define MFMA(a,b,c) __builtin_amdgcn_mfma_f32_16x16x32_bf16(a,b,c,0,0,0)

__device__ __forceinline__ float fast_tanh(float x){
    float e = __expf(2.0f*x);
    return 1.0f - 2.0f*__builtin_amdgcn_rcpf(e+1.0f);
}
__device__ __forceinline__ unsigned bfr(float x){
    unsigned u = __float_as_uint(x);
    return (u + 0x7fffu + ((u>>16)&1u)) >> 16;
}
__device__ __forceinline__ unsigned pk2(float lo, float hi){
    return bfr(lo) | (bfr(hi)<<16);
}
__device__ __forceinline__ float bf2f(unsigned short s){
    return __uint_as_float(((unsigned)s)<<16);
}
__device__ __forceinline__ short8 fragld(const unsigned* p){
    union { uint4 u; short8 s; } cv;
    cv.u = *(const uint4*)p;
    return cv.s;
}

// ---------------- kW: pack all weights as A-fragments (pack16 of W^T), compute M, u, w2t ----
__global__ __launch_bounds__(256) void kW(const float* __restrict__ se_w,
        const float* __restrict__ sap_w, const float* __restrict__ av_w,
        const float* __restrict__ f1_w, const float* __restrict__ qw,
        const float* __restrict__ kw, const float* __restrict__ qb,
        const float* __restrict__ w2,
        unsigned* __restrict__ ws){
    int idx = blockIdx.x*256 + threadIdx.x;
    if (idx < 4096){                       // sePk (F=64 pad, rows f2=128)
        int w = idx, tile = w>>9, rem = w&511;
        int ft = rem>>6, r2 = (rem>>2)&15, wi = rem&3;
        int f2 = tile*16 + r2, f1 = ft*8 + wi*2;
        float lo = (f1   < 42)? se_w[f1*128+f2]     : 0.f;
        float hi = (f1+1 < 42)? se_w[(f1+1)*128+f2] : 0.f;
        ws[OFF_SE + w] = pk2(lo,hi);
    } else if (idx < 8192){                // sapPk (F=64 pad, limit 47)
        int w = idx-4096, tile = w>>9, rem = w&511;
        int ft = rem>>6, r2 = (rem>>2)&15, wi = rem&3;
        int f2 = tile*16 + r2, f1 = ft*8 + wi*2;
        float lo = (f1   < 47)? sap_w[f1*128+f2]     : 0.f;
        float hi = (f1+1 < 47)? sap_w[(f1+1)*128+f2] : 0.f;
        ws[OFF_SAP + w] = pk2(lo,hi);
    } else if (idx < 16384){               // avPk (F=128)
        int w = idx-8192, tile = w>>10, rem = w&1023;
        int ft = rem>>6, r2 = (rem>>2)&15, wi = rem&3;
        int f2 = tile*16 + r2, f1 = ft*8 + wi*2;
        ws[OFF_AV + w] = pk2(av_w[f1*128+f2], av_w[(f1+1)*128+f2]);
    } else if (idx < 20480){               // f1Pk (F=128, rows f2=64)
        int w = idx-16384, tile = w>>10, rem = w&1023;
        int ft = rem>>6, r2 = (rem>>2)&15, wi = rem&3;
        int f2 = tile*16 + r2, f1 = ft*8 + wi*2;
        ws[OFF_F1 + w] = pk2(f1_w[f1*64+f2], f1_w[(f1+1)*64+f2]);
    } else if (idx < 28672){               // MPk: M[e][f2] = qw[e]·kw[f2]
        int w = idx-20480, tile = w>>10, rem = w&1023;
        int ft = rem>>6, r2 = (rem>>2)&15, wi = rem&3;
        int f2 = tile*16 + r2, e0 = ft*8 + wi*2;
        float lo=0.f, hi=0.f;
        for (int d=0; d<128; ++d){
            float kv = kw[f2*128+d];
            lo += qw[e0*128+d]*kv;
            hi += qw[(e0+1)*128+d]*kv;
        }
        ws[OFF_M + w] = pk2(lo,hi);
    } else if (idx < 28800){               // u[f] = qb·kw[f]
        int f = idx-28672;
        float a = 0.f;
        for (int d=0; d<128; ++d) a += qb[d]*kw[f*128+d];
        ((float*)ws)[OFF_U + f] = a;
    } else if (idx < 33408){               // w2t[k][oc] = w2[oc][k]
        int w = idx-28800;
        int k = w>>5, oc = w&31;
        ((float*)ws)[OFF_W2T + w] = w2[oc*144 + k];
    }
}

// ---------------- kF: conv (4 passes, states stay in LDS) + fused attention/SAP/AV/f1/mix --
// grid 512, 256 threads = 4 waves = 4 tiles = 64 agents = 8 batches per block.
__global__ __launch_bounds__(256,2) void kF(const unsigned* __restrict__ ws,
        const float* __restrict__ xin, const float* __restrict__ pos,
        const float* __restrict__ oneh, const float* __restrict__ acts,
        const float* __restrict__ pols,
        const float* __restrict__ w1, const float* __restrict__ b1,
        const float* __restrict__ b2,
        const float* __restrict__ se_b,
        const float* __restrict__ sap_b, const float* __restrict__ av_b,
        const float* __restrict__ f1_b, const float* __restrict__ f2_w,
        const float* __restrict__ f2_b,
        float* __restrict__ wout, float* __restrict__ value){
    __shared__ unsigned SM[9216];     // overlay: conv{w2t,in,h1,ap,pose,w1,b1,b2} | AB{stage[2][2048], U1[5120]}
    __shared__ unsigned stPk[4096];   // persistent state packs: A[4*512] | P[4*512]
    __shared__ unsigned sA64[2176];   // bf16 [64 rows][68]
    __shared__ unsigned sP64[2176];
    __shared__ float s_w[512];
    __shared__ float s_bias[384];     // sap_b | av_b | f1_b | f2_w
    __shared__ float s_ub[256];       // u | se_b
    const int t = threadIdx.x;
    const int wv = t>>6, lane = t&63;
    const int g = lane>>4, c = lane&15;

    // ===== Phase C: conv encoder, 4 passes of 16 agents =====
    float* c_w2t = (float*)SM;              // 4608
    float* c_in  = (float*)(SM+4608);       // 1216
    float* c_h1  = (float*)(SM+5824);       // 2448
    float* c_ap  = (float*)(SM+8272);       // 160
    float* c_pose= (float*)(SM+8432);       // 160
    float* c_w1  = (float*)(SM+8592);       // 432
    float* c_b1  = (float*)(SM+9024);       // 16
    float* c_b2  = (float*)(SM+9040);       // 32  (ends 9072 <= 9216)
    {
        const float* wsW2T = (const float*)(ws + OFF_W2T);
        for (int q=t; q<1152; q+=256)
            *(float4*)&c_w2t[q*4] = *(const float4*)&wsW2T[q*4];
        for (int q=t; q<432; q+=256) c_w1[q] = w1[q];
        if (t<16) c_b1[t] = b1[t];
        if (t<32) c_b2[t] = b2[t];
    }
    for (int q=t; q<384; q+=256)
        s_bias[q] = (q<128)? sap_b[q] : (q<256)? av_b[q-128] : (q<320)? f1_b[q-256] : f2_w[q-320];
    s_ub[t] = (t<128)? ((const float*)ws)[OFF_U+t] : se_b[t-128];

    for (int p=0; p<4; ++p){
        const size_t a0g = (size_t)blockIdx.x*64 + p*16;
        for (int q=t; q<1200; q+=256){
            int ag=q/75, r=q-ag*75;
            c_in[ag*76+r] = xin[a0g*75+q];
        }
        for (int q=t; q<160; q+=256){
            int ag=q/10, k=q-ag*10;
            c_ap[q]   = (k<5)? acts[(a0g+ag)*5+k] : pols[(a0g+ag)*5+(k-5)];
            c_pose[q] = (k<2)? pos[(a0g+ag)*2+k]  : oneh[(a0g+ag)*8+(k-2)];
        }
        __syncthreads();
        // conv1: thread = (ag = t&15, oc = t>>4)
        {
            const int ag = t&15, oc = t>>4;
            float w[27];
            #pragma unroll
            for (int i=0;i<27;++i) w[i]=c_w1[oc*27+i];
            float out[9];
            float bb = c_b1[oc];
            #pragma unroll
            for (int q=0;q<9;++q) out[q]=bb;
            #pragma unroll
            for (int ic=0;ic<3;++ic){
                float pin[25];
                #pragma unroll
                for (int i=0;i<25;++i) pin[i]=c_in[ag*76+ic*25+i];
                #pragma unroll
                for (int y=0;y<3;++y)
                  #pragma unroll
                  for (int x=0;x<3;++x)
                    #pragma unroll
                    for (int ky=0;ky<3;++ky)
                      #pragma unroll
                      for (int kx=0;kx<3;++kx)
                        out[y*3+x] += pin[(y+ky)*5+(x+kx)] * w[ic*9+ky*3+kx];
            }
            #pragma unroll
            for (int q=0;q<9;++q){
                float v = out[q];
                v = (v>=0.f)? v : 0.01f*v;
                c_h1[(oc*9+q)*17 + ag] = v;
            }
        }
        __syncthreads();
        // conv2 + pack: thread = (ag = t>>4, oc pair = (t&15)*2)
        {
            const int ag = t>>4, o2 = t&15, oc = o2*2;
            float a0 = c_b2[oc], a1 = c_b2[oc+1];
            #pragma unroll 8
            for (int k=0;k<144;++k){
                float h = c_h1[k*17+ag];
                float2 wv2 = *(const float2*)&c_w2t[k*32+oc];
                a0 += h*wv2.x; a1 += h*wv2.y;
            }
            a0 = (a0>=0.f)? a0 : 0.01f*a0;
            a1 = (a1>=0.f)? a1 : 0.01f*a1;
            unsigned pw = pk2(a0,a1);
            int word = p*512 + (o2>>2)*64 + ag*4 + (o2&3);
            stPk[word] = pw;
            stPk[2048+word] = pw;
        }
        // pose/act/pol pack words (ft 4..7)
        {
            const int ft4 = t>>6, r = (t>>2)&15, wi = t&3;
            const int f0 = 32 + ft4*8 + wi*2;
            float a0=0.f,a1=0.f,p0=0.f,p1=0.f;
            if (f0 < 42){ a0 = c_pose[r*10 + f0-32]; p0 = a0; }
            else if (f0 < 47){ a0 = c_ap[r*10 + f0-42]; p0 = c_ap[r*10+5 + f0-42]; }
            if (f0+1 < 42){ a1 = c_pose[r*10 + f0-31]; p1 = a1; }
            else if (f0+1 < 47){ a1 = c_ap[r*10 + f0-41]; p1 = c_ap[r*10+5 + f0-41]; }
            int word = p*512 + (4+ft4)*64 + r*4 + wi;
            stPk[word]      = pk2(a0,a1);
            stPk[2048+word] = pk2(p0,p1);
        }
        __syncthreads();
    }

    // ===== Phase AB =====
    const int tile = blockIdx.x*4 + wv;
    short8 bfA0 = fragld(&stPk[wv*512 + lane*4]);
    short8 bfA1 = fragld(&stPk[wv*512 + 256 + lane*4]);
    short8 bfP0 = fragld(&stPk[2048 + wv*512 + lane*4]);
    short8 bfP1 = fragld(&stPk[2048 + wv*512 + 256 + lane*4]);
    unsigned (*s_stage)[2048] = (unsigned (*)[2048])&SM[0];
    unsigned* U1 = &SM[4096];
    unsigned* wS = &U1[wv*1280];          // 1024-word per-wave repack scratch
    unsigned* tS = &U1[wv*1280 + 1024];   // 256-word T scratch

    uint4 r0, r1;
#define PREF(off) { r0 = *(const uint4*)(ws + (off) + t*4); \
                    r1 = *(const uint4*)(ws + (off) + 1024 + t*4); }
#define WR(b) { *(uint4*)&s_stage[b][t*4] = r0; *(uint4*)&s_stage[b][1024 + t*4] = r1; }

    PREF(OFF_SE); WR(0);
    __syncthreads();

    // ---- SE chunks c0,c1 -> acc[8] ----
    f32x4 acc[8];
    #pragma unroll
    for (int i=0;i<8;++i) acc[i] = (f32x4){0.f,0.f,0.f,0.f};
    PREF(OFF_SE + 2048);
    #pragma unroll
    for (int ft=0; ft<4; ++ft){
        short8 a0 = fragld(&s_stage[0][ft*512 + lane*4]);
        short8 a1 = fragld(&s_stage[0][ft*512 + 256 + lane*4]);
        acc[ft] = MFMA(a0, bfA0, acc[ft]);
        acc[ft] = MFMA(a1, bfA1, acc[ft]);
    }
    WR(1); __syncthreads();
    PREF(OFF_M);
    #pragma unroll
    for (int ft=4; ft<8; ++ft){
        short8 a0 = fragld(&s_stage[1][(ft-4)*512 + lane*4]);
        short8 a1 = fragld(&s_stage[1][(ft-4)*512 + 256 + lane*4]);
        acc[ft] = MFMA(a0, bfA0, acc[ft]);
        acc[ft] = MFMA(a1, bfA1, acc[ft]);
    }
    WR(0);
    // E build -> wS, cache ef[4]
    #pragma unroll
    for (int ft=0; ft<8; ++ft){
        const float* bp = &s_ub[128 + ft*16 + g*4];
        float d0 = fast_tanh(acc[ft][0]+bp[0]);
        float d1 = fast_tanh(acc[ft][1]+bp[1]);
        float d2 = fast_tanh(acc[ft][2]+bp[2]);
        float d3 = fast_tanh(acc[ft][3]+bp[3]);
        int word = (2*ft + (g>>1))*64 + c*4 + (g&1)*2;
        *(uint2*)&wS[word] = make_uint2(pk2(d0,d1), pk2(d2,d3));
    }
    short8 ef[4];
    #pragma unroll
    for (int kt=0; kt<4; ++kt) ef[kt] = fragld(&wS[kt*256 + lane*4]);
    __syncthreads();

    // ---- M chunks c2..c5, fused T-write + logits ----
    f32x4 L = (f32x4){0.f,0.f,0.f,0.f};
    #pragma unroll
    for (int i=0; i<4; ++i){
        const int nextOff = (i<3)? (OFF_M + (i+1)*2048) : OFF_SAP;
        PREF(nextOff);
        f32x4 a2[2];
        a2[0] = (f32x4){0.f,0.f,0.f,0.f};
        a2[1] = (f32x4){0.f,0.f,0.f,0.f};
        #pragma unroll
        for (int ftl=0; ftl<2; ++ftl)
          #pragma unroll
          for (int kt=0; kt<4; ++kt){
            short8 mf = fragld(&s_stage[i&1][ftl*1024 + kt*256 + lane*4]);
            a2[ftl] = MFMA(mf, ef[kt], a2[ftl]);
          }
        WR((i+1)&1);
        #pragma unroll
        for (int ftl=0; ftl<2; ++ftl){
            const float* up = &s_ub[(2*i+ftl)*16 + g*4];
            int word = (2*ftl + (g>>1))*64 + c*4 + (g&1)*2;
            *(uint2*)&tS[word] = make_uint2(pk2(a2[ftl][0]+up[0], a2[ftl][1]+up[1]),
                                            pk2(a2[ftl][2]+up[2], a2[ftl][3]+up[3]));
        }
        short8 tf = fragld(&tS[lane*4]);
        L = MFMA(tf, ef[i], L);
        __syncthreads();
    }
    // softmax -> s_w + wout
    {
        float sc[4];
        #pragma unroll
        for (int q=0;q<4;++q) sc[q] = L[q]*0.08838834764831845f;
        #pragma unroll
        for (int q=0;q<4;++q){
            float m = sc[q];
            m = fmaxf(m, __shfl_xor(m,1));
            m = fmaxf(m, __shfl_xor(m,2));
            m = fmaxf(m, __shfl_xor(m,4));
            float ex = __expf(sc[q]-m);
            float su = ex;
            su += __shfl_xor(su,1);
            su += __shfl_xor(su,2);
            su += __shfl_xor(su,4);
            sc[q] = ex/su;
        }
        if ((c>>3) == (g>>1)){
            int lb = wv*2 + (g>>1);
            int batch = tile*2 + (g>>1);
            int idx = ((g&1)*4)*8 + (c&7);
            #pragma unroll
            for (int q=0;q<4;++q){
                float v = sc[q];
                wout[batch*64 + idx + q*8] = v;
                s_w[lb*64 + idx + q*8] = v;
            }
        }
    }

    // ---- SAP chunks c6,c7 -> aS[2][8] ----
    f32x4 aS[2][8];
    #pragma unroll
    for (int v=0;v<2;++v)
      #pragma unroll
      for (int i=0;i<8;++i) aS[v][i] = (f32x4){0.f,0.f,0.f,0.f};
    PREF(OFF_SAP + 2048);
    #pragma unroll
    for (int ft=0; ft<4; ++ft){
        short8 a0 = fragld(&s_stage[0][ft*512 + lane*4]);
        short8 a1 = fragld(&s_stage[0][ft*512 + 256 + lane*4]);
        aS[0][ft] = MFMA(a0, bfA0, aS[0][ft]);
        aS[0][ft] = MFMA(a1, bfA1, aS[0][ft]);
        aS[1][ft] = MFMA(a0, bfP0, aS[1][ft]);
        aS[1][ft] = MFMA(a1, bfP1, aS[1][ft]);
    }
    WR(1); __syncthreads();
    PREF(OFF_AV);
    #pragma unroll
    for (int ft=4; ft<8; ++ft){
        short8 a0 = fragld(&s_stage[1][(ft-4)*512 + lane*4]);
        short8 a1 = fragld(&s_stage[1][(ft-4)*512 + 256 + lane*4]);
        aS[0][ft] = MFMA(a0, bfA0, aS[0][ft]);
        aS[0][ft] = MFMA(a1, bfA1, aS[0][ft]);
        aS[1][ft] = MFMA(a0, bfP0, aS[1][ft]);
        aS[1][ft] = MFMA(a1, bfP1, aS[1][ft]);
    }
    WR(0);
    // SAP build (variant A then P through the single scratch), cache frags
    short8 spA[4], spP[4];
    #pragma unroll
    for (int ft=0; ft<8; ++ft){
        const float* bp = &s_bias[ft*16 + g*4];
        float d0 = fast_tanh(aS[0][ft][0]+bp[0]);
        float d1 = fast_tanh(aS[0][ft][1]+bp[1]);
        float d2 = fast_tanh(aS[0][ft][2]+bp[2]);
        float d3 = fast_tanh(aS[0][ft][3]+bp[3]);
        int word = (2*ft + (g>>1))*64 + c*4 + (g&1)*2;
        *(uint2*)&wS[word] = make_uint2(pk2(d0,d1), pk2(d2,d3));
    }
    #pragma unroll
    for (int kt=0; kt<4; ++kt) spA[kt] = fragld(&wS[kt*256 + lane*4]);
    #pragma unroll
    for (int ft=0; ft<8; ++ft){
        const float* bp = &s_bias[ft*16 + g*4];
        float d0 = fast_tanh(aS[1][ft][0]+bp[0]);
        float d1 = fast_tanh(aS[1][ft][1]+bp[1]);
        float d2 = fast_tanh(aS[1][ft][2]+bp[2]);
        float d3 = fast_tanh(aS[1][ft][3]+bp[3]);
        int word = (2*ft + (g>>1))*64 + c*4 + (g&1)*2;
        *(uint2*)&wS[word] = make_uint2(pk2(d0,d1), pk2(d2,d3));
    }
    #pragma unroll
    for (int kt=0; kt<4; ++kt) spP[kt] = fragld(&wS[kt*256 + lane*4]);
    __syncthreads();

    // ---- AV chunks c8..c11 -> aV[2][8] ----
    f32x4 aV[2][8];
    #pragma unroll
    for (int v=0;v<2;++v)
      #pragma unroll
      for (int i=0;i<8;++i) aV[v][i] = (f32x4){0.f,0.f,0.f,0.f};
    short8 avA[4], avP[4];
    #pragma unroll
    for (int i=0; i<4; ++i){
        const int nextOff = (i<3)? (OFF_AV + (i+1)*2048) : OFF_F1;
        PREF(nextOff);
        #pragma unroll
        for (int ftl=0; ftl<2; ++ftl){
            const int ft = 2*i + ftl;
            #pragma unroll
            for (int kt=0; kt<4; ++kt){
                short8 af = fragld(&s_stage[i&1][ftl*1024 + kt*256 + lane*4]);
                aV[0][ft] = MFMA(af, spA[kt], aV[0][ft]);
                aV[1][ft] = MFMA(af, spP[kt], aV[1][ft]);
            }
        }
        WR((i+1)&1);
        if (i==3){
            // AV build (A then P through scratch), cache frags
            #pragma unroll
            for (int ft=0; ft<8; ++ft){
                const float* bp = &s_bias[128 + ft*16 + g*4];
                float d0 = fast_tanh(aV[0][ft][0]+bp[0]);
                float d1 = fast_tanh(aV[0][ft][1]+bp[1]);
                float d2 = fast_tanh(aV[0][ft][2]+bp[2]);
                float d3 = fast_tanh(aV[0][ft][3]+bp[3]);
                int word = (2*ft + (g>>1))*64 + c*4 + (g&1)*2;
                *(uint2*)&wS[word] = make_uint2(pk2(d0,d1), pk2(d2,d3));
            }
            #pragma unroll
            for (int kt=0; kt<4; ++kt) avA[kt] = fragld(&wS[kt*256 + lane*4]);
            #pragma unroll
            for (int ft=0; ft<8; ++ft){
                const float* bp = &s_bias[128 + ft*16 + g*4];
                float d0 = fast_tanh(aV[1][ft][0]+bp[0]);
                float d1 = fast_tanh(aV[1][ft][1]+bp[1]);
                float d2 = fast_tanh(aV[1][ft][2]+bp[2]);
                float d3 = fast_tanh(aV[1][ft][3]+bp[3]);
                int word = (2*ft + (g>>1))*64 + c*4 + (g&1)*2;
                *(uint2*)&wS[word] = make_uint2(pk2(d0,d1), pk2(d2,d3));
            }
            #pragma unroll
            for (int kt=0; kt<4; ++kt) avP[kt] = fragld(&wS[kt*256 + lane*4]);
        }
        __syncthreads();
    }

    // ---- F1 chunks c12,c13 -> aF[2][4] ----
    f32x4 aF[2][4];
    #pragma unroll
    for (int v=0;v<2;++v)
      #pragma unroll
      for (int i=0;i<4;++i) aF[v][i] = (f32x4){0.f,0.f,0.f,0.f};
    PREF(OFF_F1 + 2048);
    #pragma unroll
    for (int ftl=0; ftl<2; ++ftl)
      #pragma unroll
      for (int kt=0; kt<4; ++kt){
        short8 af = fragld(&s_stage[0][ftl*1024 + kt*256 + lane*4]);
        aF[0][ftl] = MFMA(af, avA[kt], aF[0][ftl]);
        aF[1][ftl] = MFMA(af, avP[kt], aF[1][ftl]);
      }
    WR(1); __syncthreads();
    #pragma unroll
    for (int ftl=0; ftl<2; ++ftl)
      #pragma unroll
      for (int kt=0; kt<4; ++kt){
        short8 af = fragld(&s_stage[1][ftl*1024 + kt*256 + lane*4]);
        aF[0][2+ftl] = MFMA(af, avA[kt], aF[0][2+ftl]);
        aF[1][2+ftl] = MFMA(af, avP[kt], aF[1][2+ftl]);
      }
    {
        int row = wv*16 + c;
        #pragma unroll
        for (int v=0;v<2;++v){
            unsigned* dst = v? sP64 : sA64;
            #pragma unroll
            for (int ft=0; ft<4; ++ft){
                int idx = row*34 + ft*8 + 2*g;
                *(uint2*)&dst[idx] = make_uint2(pk2(aF[v][ft][0], aF[v][ft][1]),
                                                pk2(aF[v][ft][2], aF[v][ft][3]));
            }
        }
    }
    __syncthreads();
    // ---- tail: b64 + final mix ----
    float* s_b64 = (float*)U1;  // [64 rows][68]
    const unsigned short* A16 = (const unsigned short*)sA64;
    const unsigned short* P16 = (const unsigned short*)sP64;
    #pragma unroll
    for (int k=0; k<16; ++k){
        int e = t + 256*k;
        int bq = e>>9, a = (e>>6)&7, cc = e&63;
        const float* wp = &s_w[bq*64 + a*8];
        float acc4 = 0.f;
        #pragma unroll
        for (int j=0;j<8;++j) acc4 += wp[j]*bf2f(A16[(bq*8+j)*68 + cc]);
        s_b64[(bq*8+a)*68 + cc] = acc4;
    }
    __syncthreads();
    #pragma unroll
    for (int k=0; k<2; ++k){
        int o = t + 256*k;
        int bq = o>>6, a = (o>>3)&7, i = o&7;
        float w_ai = s_w[bq*64 + a*8 + i];
        const float* pb = &s_b64[(bq*8+a)*68];
        const unsigned short* pA = &A16[(bq*8+i)*68];
        const unsigned short* pP = &P16[(bq*8+i)*68];
        float acc5 = 0.f;
        #pragma unroll 8
        for (int cc=0; cc<64; ++cc){
            float dd = bf2f(pP[cc]) - bf2f(pA[cc]);
            acc5 += fast_tanh(pb[cc] + w_ai*dd + s_bias[256+cc]) * s_bias[320+cc];
        }
        value[(size_t)blockIdx.x*512 + o] = acc5 + f2_b[0];
    }
#undef PREF
#undef WR
}

extern "C" void kernel_launch(void* const* d_in, const int* in_sizes, int n_in,
                              void* d_out, int out_size, void* d_ws, size_t ws_size,
                              hipStream_t stream){
    const float* agent_states = (const float*)d_in[0];
    const float* pos    = (const float*)d_in[1];
    const float* oneh   = (const float*)d_in[2];
    const float* pols   = (const float*)d_in[3];
    const float* acts   = (const float*)d_in[4];
    const float* w1     = (const float*)d_in[5];
    const float* b1     = (const float*)d_in[6];
    const float* w2     = (const float*)d_in[7];
    const float* b2     = (const float*)d_in[8];
    const float* se_w   = (const float*)d_in[9];
    const float* se_b   = (const float*)d_in[10];
    const float* key_w  = (const float*)d_in[11];
    const float* query_w= (const float*)d_in[13];
    const float* query_b= (const float*)d_in[14];
    const float* sap_w  = (const float*)d_in[15];
    const float* sap_b  = (const float*)d_in[16];
    const float* av_w   = (const float*)d_in[17];
    const float* av_b   = (const float*)d_in[18];
    const float* f1_w   = (const float*)d_in[19];
    const float* f1_b   = (const float*)d_in[20];
    const float* f2_w   = (const float*)d_in[21];
    const float* f2_b   = (const float*)d_in[22];

    unsigned* ws = (unsigned*)d_ws;

    float* value = (float*)d_out;
    float* wout  = value + (size_t)NB*NA*NA;

    kW<<<131, 256, 0, stream>>>(se_w, sap_w, av_w, f1_w, query_w, key_w, query_b, w2, ws);
    kF<<<BN/64, 256, 0, stream>>>(ws, agent_states, pos, oneh, acts, pols,
                                  w1, b1, b2, se_b, sap_b, av_b, f1_b, f2_w, f2_b,
                                  wout, value);
}